// Round 1
// baseline (1591.219 us; speedup 1.0000x reference)
//
#include <hip/hip_runtime.h>
#include <stdint.h>

#define VOCABN 8000
#define EE     300
#define HH     75
#define G4     300   // 4*H
#define TT     6
#define BB     256
#define SS     512
#define STARTT 4
#define STOPT  5
#define NEGV   (-10000.0f)

// padded dims for the vocab GEMM
#define EP 304   // 19*16
#define VP 8064  // 63*128
#define GP 320   // 5*64

__device__ __forceinline__ float fast_sigmoid(float x){
  return __builtin_amdgcn_rcpf(1.0f + __expf(-x));
}
__device__ __forceinline__ float fast_tanh(float x){
  x = fminf(15.0f, fmaxf(-15.0f, x));
  float e = __expf(2.0f * x);
  return (e - 1.0f) * __builtin_amdgcn_rcpf(e + 1.0f);
}

// ---------------- K0: zero-padded copies of emb and w_ih (both dirs) ----------
__global__ __launch_bounds__(256) void k_prep(
    const float* __restrict__ emb, const float* __restrict__ wf,
    const float* __restrict__ wb, float* __restrict__ embp, float* __restrict__ wp){
  const int n1 = VP * EP;
  const int n2 = GP * EP;
  const int ntot = n1 + 2 * n2;
  for (int i = blockIdx.x * 256 + threadIdx.x; i < ntot; i += gridDim.x * 256){
    if (i < n1){
      int v = i / EP, e = i % EP;
      embp[i] = (v < VOCABN && e < EE) ? emb[v * EE + e] : 0.f;
    } else {
      int jj = i - n1;
      int d = jj / n2, r = jj % n2;
      int g = r / EP, e = r % EP;
      const float* w = d ? wb : wf;
      wp[jj] = (g < G4 && e < EE) ? w[g * EE + e] : 0.f;
    }
  }
}

// ---------------- K1: vocab_xg[dir][v][g] = emb[v] . w_ih[g] + b_ih[g]+b_hh[g]
// tile 128v x 64g, K-chunk 16, per-thread 8x4 register tile.
#define LDSR 20  // LDS row stride in floats (80B, 16B-aligned)
__global__ __launch_bounds__(256) void k_gemm(
    const float* __restrict__ embp, const float* __restrict__ wp,
    const float* __restrict__ b_ih_f, const float* __restrict__ b_hh_f,
    const float* __restrict__ b_ih_b, const float* __restrict__ b_hh_b,
    float* __restrict__ vxg){
  __shared__ alignas(16) float a_sh[128 * LDSR];
  __shared__ alignas(16) float b_sh[64 * LDSR];
  __shared__ float bias_sh[64];
  const int bx = blockIdx.x;           // dir*(63*5) + vt*5 + gt
  const int dir = bx / (63 * 5);
  const int rem = bx % (63 * 5);
  const int vt = rem / 5, gt = rem % 5;
  const int v0 = vt * 128, g0 = gt * 64;
  const int tid = threadIdx.x;
  const float* wdir = wp + (size_t)dir * GP * EP;

  if (tid < 64){
    int g = g0 + tid;
    float bi = 0.f;
    if (g < G4) bi = dir ? (b_ih_b[g] + b_hh_b[g]) : (b_ih_f[g] + b_hh_f[g]);
    bias_sh[tid] = bi;
  }

  float acc[8][4];
  #pragma unroll
  for (int i = 0; i < 8; ++i)
    #pragma unroll
    for (int j = 0; j < 4; ++j) acc[i][j] = 0.f;

  const int tx = tid & 15, ty = tid >> 4;
  const int la_r = tid >> 1, la_h = (tid & 1) * 8;
  const int lb_r = tid >> 2, lb_h = (tid & 3) * 4;

  for (int kk = 0; kk < 19; ++kk){
    const int e0 = kk * 16;
    float4 av0 = *(const float4*)&embp[(size_t)(v0 + la_r) * EP + e0 + la_h];
    float4 av1 = *(const float4*)&embp[(size_t)(v0 + la_r) * EP + e0 + la_h + 4];
    float4 bv  = *(const float4*)&wdir[(size_t)(g0 + lb_r) * EP + e0 + lb_h];
    __syncthreads();
    *(float4*)&a_sh[la_r * LDSR + la_h]     = av0;
    *(float4*)&a_sh[la_r * LDSR + la_h + 4] = av1;
    *(float4*)&b_sh[lb_r * LDSR + lb_h]     = bv;
    __syncthreads();
    #pragma unroll
    for (int e4 = 0; e4 < 4; ++e4){
      float4 bq[4], aq[8];
      #pragma unroll
      for (int j = 0; j < 4; ++j) bq[j] = *(const float4*)&b_sh[(tx + 16 * j) * LDSR + e4 * 4];
      #pragma unroll
      for (int i = 0; i < 8; ++i) aq[i] = *(const float4*)&a_sh[(ty + 16 * i) * LDSR + e4 * 4];
      #pragma unroll
      for (int i = 0; i < 8; ++i)
        #pragma unroll
        for (int j = 0; j < 4; ++j)
          acc[i][j] += aq[i].x * bq[j].x + aq[i].y * bq[j].y
                     + aq[i].z * bq[j].z + aq[i].w * bq[j].w;
    }
  }

  const size_t obase = (size_t)dir * VOCABN * G4;
  #pragma unroll
  for (int i = 0; i < 8; ++i){
    int v = v0 + ty + 16 * i;
    if (v < VOCABN){
      #pragma unroll
      for (int j = 0; j < 4; ++j){
        int g = g0 + tx + 16 * j;
        if (g < G4) vxg[obase + (size_t)v * G4 + g] = acc[i][j] + bias_sh[tx + 16 * j];
      }
    }
  }
}

// ---------------- K2: per-(dir,batch) LSTM recurrence, feats fused -----------
__device__ __forceinline__ float dot75(const float* __restrict__ h_sh,
                                       const float w[76], float init){
  const float4* h4 = (const float4*)h_sh;
  float a0 = init, a1 = 0.f, a2 = 0.f, a3 = 0.f;
  #pragma unroll
  for (int q = 0; q < 19; ++q){
    float4 hv = h4[q];
    a0 += hv.x * w[4 * q + 0];
    a1 += hv.y * w[4 * q + 1];
    a2 += hv.z * w[4 * q + 2];
    a3 += hv.w * w[4 * q + 3];
  }
  return (a0 + a1) + (a2 + a3);
}

__global__ __launch_bounds__(320) void k_lstm(
    const int* __restrict__ sentence, const float* __restrict__ vxg,
    const float* __restrict__ w_hh_f, const float* __restrict__ w_hh_b,
    const float* __restrict__ h0, const float* __restrict__ c0,
    const float* __restrict__ w_out, const float* __restrict__ b_out,
    float* __restrict__ featsF, float* __restrict__ featsB){
  __shared__ alignas(16) float h_sh[76];
  __shared__ float gates_sh[G4];
  __shared__ int tok_sh[SS];
  const int bx = blockIdx.x;
  const int dir = bx >> 8;
  const int b = bx & 255;
  const int t = threadIdx.x;

  for (int i = t; i < SS; i += 320) tok_sh[i] = sentence[b * SS + i];

  float w[76];
  if (t < G4){
    const float* whh = dir ? w_hh_b : w_hh_f;
    #pragma unroll
    for (int j = 0; j < HH; ++j) w[j] = whh[t * HH + j];
    w[75] = 0.f;
  } else if (t < G4 + TT){
    const int tt = t - G4;
    #pragma unroll
    for (int j = 0; j < HH; ++j) w[j] = w_out[tt * (2 * HH) + dir * HH + j];
    w[75] = 0.f;
  }
  float c = 0.f;
  if (t < HH){
    h_sh[t] = h0[((size_t)dir * BB + b) * HH + t];
    c       = c0[((size_t)dir * BB + b) * HH + t];
  }
  if (t == HH) h_sh[HH] = 0.f;
  __syncthreads();

  const float* vx = vxg + (size_t)dir * VOCABN * G4;
  float* feats = dir ? featsB : featsF;
  const float bout = (dir == 0 && t >= G4 && t < G4 + TT) ? b_out[t - G4] : 0.f;

  float cur = (t < G4) ? vx[(size_t)tok_sh[dir ? (SS - 1) : 0] * G4 + t] : 0.f;
  int prev_s = 0;
  for (int k = 0; k <= SS; ++k){
    if (t < G4){
      if (k < SS){
        float nxt = 0.f;
        if (k + 1 < SS){
          int s1 = dir ? (SS - 2 - k) : (k + 1);
          nxt = vx[(size_t)tok_sh[s1] * G4 + t];     // prefetch next step's xg
        }
        gates_sh[t] = dot75(h_sh, w, cur);
        cur = nxt;
      }
    } else if (t < G4 + TT && k > 0){
      float val = dot75(h_sh, w, bout);              // feats for previous h
      feats[((size_t)prev_s * BB + b) * TT + (t - G4)] = val;
    }
    __syncthreads();
    if (t < HH && k < SS){
      float gi = gates_sh[t];
      float gf = gates_sh[HH + t];
      float gg = gates_sh[2 * HH + t];
      float go = gates_sh[3 * HH + t];
      c = fast_sigmoid(gf) * c + fast_sigmoid(gi) * fast_tanh(gg);
      h_sh[t] = fast_sigmoid(go) * fast_tanh(c);
    }
    __syncthreads();
    prev_s = dir ? (SS - 1 - k) : k;
  }
}

// ---------------- K3: CRF forward scan + gold score --------------------------
__device__ __forceinline__ float crf_step(float alpha, float feat, const float tr[6]){
  float v0 = __shfl(alpha, 0, 8) + tr[0];
  float v1 = __shfl(alpha, 1, 8) + tr[1];
  float v2 = __shfl(alpha, 2, 8) + tr[2];
  float v3 = __shfl(alpha, 3, 8) + tr[3];
  float v4 = __shfl(alpha, 4, 8) + tr[4];
  float v5 = __shfl(alpha, 5, 8) + tr[5];
  float m = fmaxf(fmaxf(fmaxf(v0, v1), fmaxf(v2, v3)), fmaxf(v4, v5));
  float s = __expf(v0 - m) + __expf(v1 - m) + __expf(v2 - m)
          + __expf(v3 - m) + __expf(v4 - m) + __expf(v5 - m);
  return m + __logf(s) + feat;
}

__global__ __launch_bounds__(256) void k_crf(
    const float* __restrict__ featsF, const float* __restrict__ featsB,
    const float* __restrict__ trans, const int* __restrict__ tags,
    float* __restrict__ out){
  const int tid = blockIdx.x * 256 + threadIdx.x;
  const int b = tid >> 3;
  const int l = tid & 7;
  const int j = (l < 6) ? l : 0;
  float tr[6];
  #pragma unroll
  for (int i = 0; i < 6; ++i) tr[i] = trans[j * 6 + i];

  float alpha = (l == STARTT) ? 0.f : NEGV;
  const size_t stride = (size_t)BB * TT;
  const size_t base = (size_t)b * TT + j;

  float f0 = (l < 6) ? featsF[0 * stride + base] + featsB[0 * stride + base] : 0.f;
  float f1 = (l < 6) ? featsF[1 * stride + base] + featsB[1 * stride + base] : 0.f;
  float f2 = (l < 6) ? featsF[2 * stride + base] + featsB[2 * stride + base] : 0.f;
  float f3 = (l < 6) ? featsF[3 * stride + base] + featsB[3 * stride + base] : 0.f;

  for (int s = 0; s < SS; s += 4){
    alpha = crf_step(alpha, f0, tr);
    f0 = (l < 6 && s + 4 < SS) ? featsF[(size_t)(s + 4) * stride + base] + featsB[(size_t)(s + 4) * stride + base] : 0.f;
    alpha = crf_step(alpha, f1, tr);
    f1 = (l < 6 && s + 5 < SS) ? featsF[(size_t)(s + 5) * stride + base] + featsB[(size_t)(s + 5) * stride + base] : 0.f;
    alpha = crf_step(alpha, f2, tr);
    f2 = (l < 6 && s + 6 < SS) ? featsF[(size_t)(s + 6) * stride + base] + featsB[(size_t)(s + 6) * stride + base] : 0.f;
    alpha = crf_step(alpha, f3, tr);
    f3 = (l < 6 && s + 7 < SS) ? featsF[(size_t)(s + 7) * stride + base] + featsB[(size_t)(s + 7) * stride + base] : 0.f;
  }

  float fin = alpha + trans[STOPT * 6 + j];
  float u0 = __shfl(fin, 0, 8), u1 = __shfl(fin, 1, 8), u2 = __shfl(fin, 2, 8);
  float u3 = __shfl(fin, 3, 8), u4 = __shfl(fin, 4, 8), u5 = __shfl(fin, 5, 8);
  float m = fmaxf(fmaxf(fmaxf(u0, u1), fmaxf(u2, u3)), fmaxf(u4, u5));
  float ssum = __expf(u0 - m) + __expf(u1 - m) + __expf(u2 - m)
             + __expf(u3 - m) + __expf(u4 - m) + __expf(u5 - m);
  float fscore = m + __logf(ssum);

  const int* tg = tags + (size_t)b * SS;
  float gold = 0.f;
  #pragma unroll 4
  for (int s = l; s < SS; s += 8){
    int curt = tg[s];
    int prv = (s == 0) ? STARTT : tg[s - 1];
    size_t fo = (size_t)s * stride + (size_t)b * TT + curt;
    gold += trans[curt * 6 + prv] + featsF[fo] + featsB[fo];
  }
  gold += __shfl_xor(gold, 4, 8);
  gold += __shfl_xor(gold, 2, 8);
  gold += __shfl_xor(gold, 1, 8);
  if (l == 0){
    gold += trans[STOPT * 6 + tg[SS - 1]];
    out[b] = fscore - gold;
  }
}

// ---------------- launch -----------------------------------------------------
extern "C" void kernel_launch(void* const* d_in, const int* in_sizes, int n_in,
                              void* d_out, int out_size, void* d_ws, size_t ws_size,
                              hipStream_t stream){
  const int*   sentence = (const int*)  d_in[0];
  const int*   tags     = (const int*)  d_in[1];
  const float* emb      = (const float*)d_in[2];
  const float* w_ih_f   = (const float*)d_in[3];
  const float* w_hh_f   = (const float*)d_in[4];
  const float* b_ih_f   = (const float*)d_in[5];
  const float* b_hh_f   = (const float*)d_in[6];
  const float* w_ih_b   = (const float*)d_in[7];
  const float* w_hh_b   = (const float*)d_in[8];
  const float* b_ih_b   = (const float*)d_in[9];
  const float* b_hh_b   = (const float*)d_in[10];
  const float* h0       = (const float*)d_in[11];
  const float* c0       = (const float*)d_in[12];
  const float* w_out    = (const float*)d_in[13];
  const float* b_out    = (const float*)d_in[14];
  const float* trans    = (const float*)d_in[15];
  float* out = (float*)d_out;

  float* ws = (float*)d_ws;
  float* vxg    = ws;                                 // [2][8000][300]
  float* embp   = vxg + (size_t)2 * VOCABN * G4;      // [8064][304]
  float* wp     = embp + (size_t)VP * EP;             // [2][320][304]
  float* featsF = wp + (size_t)2 * GP * EP;           // [512][256][6] (incl b_out)
  float* featsB = featsF + (size_t)SS * BB * TT;      // [512][256][6]

  k_prep<<<2048, 256, 0, stream>>>(emb, w_ih_f, w_ih_b, embp, wp);
  k_gemm<<<2 * 63 * 5, 256, 0, stream>>>(embp, wp, b_ih_f, b_hh_f, b_ih_b, b_hh_b, vxg);
  k_lstm<<<512, 320, 0, stream>>>(sentence, vxg, w_hh_f, w_hh_b, h0, c0, w_out, b_out,
                                  featsF, featsB);
  k_crf<<<BB * 8 / 256, 256, 0, stream>>>(featsF, featsB, trans, tags, out);
}

// Round 2
// 1139.205 us; speedup vs baseline: 1.3968x; 1.3968x over previous
//
#include <hip/hip_runtime.h>
#include <stdint.h>

#define VOCABN 8000
#define EE     300
#define HH     75
#define G4     300   // 4*H
#define TT     6
#define BB     256
#define SS     512
#define STARTT 4
#define STOPT  5
#define NEGV   (-10000.0f)

// padded dims for the vocab GEMM
#define EP 304   // 19*16
#define VP 8064  // 63*128
#define GP 320   // 5*64

__device__ __forceinline__ float fast_sigmoid(float x){
  return __builtin_amdgcn_rcpf(1.0f + __expf(-x));
}
__device__ __forceinline__ float fast_tanh(float x){
  x = fminf(15.0f, fmaxf(-15.0f, x));
  float e = __expf(2.0f * x);
  return (e - 1.0f) * __builtin_amdgcn_rcpf(e + 1.0f);
}

// raw barrier: orders LDS (lgkmcnt) but does NOT drain vmcnt -> global
// prefetches stay in flight across steps (guide §5/§6 G15 pattern).
__device__ __forceinline__ void sync_lds(){
  __builtin_amdgcn_sched_barrier(0);
  asm volatile("s_waitcnt lgkmcnt(0)" ::: "memory");
  __builtin_amdgcn_s_barrier();
  __builtin_amdgcn_sched_barrier(0);
}

#define RL(x, l) __int_as_float(__builtin_amdgcn_readlane(__float_as_int(x), (l)))

// ---------------- K0: zero-padded copies of emb and w_ih (both dirs) ----------
__global__ __launch_bounds__(256) void k_prep(
    const float* __restrict__ emb, const float* __restrict__ wf,
    const float* __restrict__ wb, float* __restrict__ embp, float* __restrict__ wp){
  const int n1 = VP * EP;
  const int n2 = GP * EP;
  const int ntot = n1 + 2 * n2;
  for (int i = blockIdx.x * 256 + threadIdx.x; i < ntot; i += gridDim.x * 256){
    if (i < n1){
      int v = i / EP, e = i % EP;
      embp[i] = (v < VOCABN && e < EE) ? emb[v * EE + e] : 0.f;
    } else {
      int jj = i - n1;
      int d = jj / n2, r = jj % n2;
      int g = r / EP, e = r % EP;
      const float* w = d ? wb : wf;
      wp[jj] = (g < G4 && e < EE) ? w[g * EE + e] : 0.f;
    }
  }
}

// ---------------- K1: vocab_xg[dir][v][g] = emb[v] . w_ih[g] + b_ih[g]+b_hh[g]
#define LDSR 20
__global__ __launch_bounds__(256) void k_gemm(
    const float* __restrict__ embp, const float* __restrict__ wp,
    const float* __restrict__ b_ih_f, const float* __restrict__ b_hh_f,
    const float* __restrict__ b_ih_b, const float* __restrict__ b_hh_b,
    float* __restrict__ vxg){
  __shared__ alignas(16) float a_sh[128 * LDSR];
  __shared__ alignas(16) float b_sh[64 * LDSR];
  __shared__ float bias_sh[64];
  const int bx = blockIdx.x;
  const int dir = bx / (63 * 5);
  const int rem = bx % (63 * 5);
  const int vt = rem / 5, gt = rem % 5;
  const int v0 = vt * 128, g0 = gt * 64;
  const int tid = threadIdx.x;
  const float* wdir = wp + (size_t)dir * GP * EP;

  if (tid < 64){
    int g = g0 + tid;
    float bi = 0.f;
    if (g < G4) bi = dir ? (b_ih_b[g] + b_hh_b[g]) : (b_ih_f[g] + b_hh_f[g]);
    bias_sh[tid] = bi;
  }

  float acc[8][4];
  #pragma unroll
  for (int i = 0; i < 8; ++i)
    #pragma unroll
    for (int j = 0; j < 4; ++j) acc[i][j] = 0.f;

  const int tx = tid & 15, ty = tid >> 4;
  const int la_r = tid >> 1, la_h = (tid & 1) * 8;
  const int lb_r = tid >> 2, lb_h = (tid & 3) * 4;

  for (int kk = 0; kk < 19; ++kk){
    const int e0 = kk * 16;
    float4 av0 = *(const float4*)&embp[(size_t)(v0 + la_r) * EP + e0 + la_h];
    float4 av1 = *(const float4*)&embp[(size_t)(v0 + la_r) * EP + e0 + la_h + 4];
    float4 bv  = *(const float4*)&wdir[(size_t)(g0 + lb_r) * EP + e0 + lb_h];
    __syncthreads();
    *(float4*)&a_sh[la_r * LDSR + la_h]     = av0;
    *(float4*)&a_sh[la_r * LDSR + la_h + 4] = av1;
    *(float4*)&b_sh[lb_r * LDSR + lb_h]     = bv;
    __syncthreads();
    #pragma unroll
    for (int e4 = 0; e4 < 4; ++e4){
      float4 bq[4], aq[8];
      #pragma unroll
      for (int j = 0; j < 4; ++j) bq[j] = *(const float4*)&b_sh[(tx + 16 * j) * LDSR + e4 * 4];
      #pragma unroll
      for (int i = 0; i < 8; ++i) aq[i] = *(const float4*)&a_sh[(ty + 16 * i) * LDSR + e4 * 4];
      #pragma unroll
      for (int i = 0; i < 8; ++i)
        #pragma unroll
        for (int j = 0; j < 4; ++j)
          acc[i][j] += aq[i].x * bq[j].x + aq[i].y * bq[j].y
                     + aq[i].z * bq[j].z + aq[i].w * bq[j].w;
    }
  }

  const size_t obase = (size_t)dir * VOCABN * G4;
  #pragma unroll
  for (int i = 0; i < 8; ++i){
    int v = v0 + ty + 16 * i;
    if (v < VOCABN){
      #pragma unroll
      for (int j = 0; j < 4; ++j){
        int g = g0 + tx + 16 * j;
        if (g < G4) vxg[obase + (size_t)v * G4 + g] = acc[i][j] + bias_sh[tx + 16 * j];
      }
    }
  }
}

// ---------------- K2: per-(dir,batch) LSTM recurrence, feats fused -----------
// 192 threads: t<150 -> gate rows t and t+150 (2 rows/thread, weights in VGPR);
// t in [150,156) -> one w_out feature row. h broadcast via 1 ds_read_b128 per
// wave + v_readlane (SGPR operand FMAs) instead of 19 b128 broadcasts.
__global__ __launch_bounds__(192) void k_lstm(
    const int* __restrict__ sentence, const float* __restrict__ vxg,
    const float* __restrict__ w_hh_f, const float* __restrict__ w_hh_b,
    const float* __restrict__ h0, const float* __restrict__ c0,
    const float* __restrict__ w_out, const float* __restrict__ b_out,
    float* __restrict__ featsF, float* __restrict__ featsB){
  __shared__ alignas(16) float h_sh[256];
  __shared__ float gates_sh[G4];
  __shared__ int tok_sh[SS];
  const int bx = blockIdx.x;
  const int dir = bx >> 8;
  const int b = bx & 255;
  const int t = threadIdx.x;
  const int lane = t & 63;

  for (int i = t; i < SS; i += 192) tok_sh[i] = sentence[b * SS + i];

  float w0[76], w1[76];
  #pragma unroll
  for (int j = 0; j < 76; ++j){ w0[j] = 0.f; w1[j] = 0.f; }
  if (t < 150){
    const float* whh = dir ? w_hh_b : w_hh_f;
    #pragma unroll
    for (int j = 0; j < HH; ++j){
      w0[j] = whh[t * HH + j];
      w1[j] = whh[(t + 150) * HH + j];
    }
  } else if (t < 156){
    #pragma unroll
    for (int j = 0; j < HH; ++j)
      w0[j] = w_out[(t - 150) * (2 * HH) + dir * HH + j];
  }
  float c = 0.f;
  if (t < HH){
    c = c0[((size_t)dir * BB + b) * HH + t];
    h_sh[t] = h0[((size_t)dir * BB + b) * HH + t];
  }
  for (int i = t + HH; i < 256; i += 192) h_sh[i] = 0.f;  // pad lanes 19..63
  __syncthreads();

  const float* vx = vxg + (size_t)dir * VOCABN * G4;
  float* feats = dir ? featsB : featsF;

  float cur0 = 0.f, cur1 = 0.f, nx0 = 0.f, nx1 = 0.f;
  if (t < 150){
    int sA = dir ? (SS - 1) : 0;
    int sB = dir ? (SS - 2) : 1;
    cur0 = vx[(size_t)tok_sh[sA] * G4 + t];
    cur1 = vx[(size_t)tok_sh[sA] * G4 + t + 150];
    nx0  = vx[(size_t)tok_sh[sB] * G4 + t];
    nx1  = vx[(size_t)tok_sh[sB] * G4 + t + 150];
  } else if (t < 156 && dir == 0){
    cur0 = b_out[t - 150];  // bias folded into feature dot init
  }

  for (int k = 0; k <= SS; ++k){
    // ---- phase A: gate dots (step k) + feature dots (step k-1) ----
    float p0 = 0.f, p1 = 0.f;
    if (t < 150 && k + 2 < SS){
      int s2 = dir ? (SS - 3 - k) : (k + 2);
      int tok2 = tok_sh[s2];
      p0 = vx[(size_t)tok2 * G4 + t];          // depth-2 prefetch, survives the
      p1 = vx[(size_t)tok2 * G4 + t + 150];    // raw barriers (no vmcnt drain)
    }
    const float4 hv = *((const float4*)h_sh + lane);
    float a0 = cur0, a1 = 0.f, a2 = 0.f, a3 = 0.f;
    float d0 = cur1, d1 = 0.f, d2 = 0.f, d3 = 0.f;
    #pragma unroll
    for (int q = 0; q < 19; ++q){
      float e0 = RL(hv.x, q), e1 = RL(hv.y, q), e2 = RL(hv.z, q), e3 = RL(hv.w, q);
      a0 += e0 * w0[4 * q + 0];  d0 += e0 * w1[4 * q + 0];
      a1 += e1 * w0[4 * q + 1];  d1 += e1 * w1[4 * q + 1];
      a2 += e2 * w0[4 * q + 2];  d2 += e2 * w1[4 * q + 2];
      a3 += e3 * w0[4 * q + 3];  d3 += e3 * w1[4 * q + 3];
    }
    float r0 = (a0 + a1) + (a2 + a3);
    float r1 = (d0 + d1) + (d2 + d3);

    if (t < 150){
      if (k < SS){
        gates_sh[t] = r0;
        gates_sh[t + 150] = r1;
        cur0 = nx0; cur1 = nx1; nx0 = p0; nx1 = p1;
      }
    } else if (t < 156 && k > 0){
      int ps = dir ? (SS - k) : (k - 1);
      feats[((size_t)ps * BB + b) * TT + (t - 150)] = r0;
    }
    if (k == SS) break;
    sync_lds();
    // ---- phase B: activations (threads 0..74) ----
    if (t < HH){
      float gi = gates_sh[t];
      float gf = gates_sh[HH + t];
      float gg = gates_sh[2 * HH + t];
      float go = gates_sh[3 * HH + t];
      c = fast_sigmoid(gf) * c + fast_sigmoid(gi) * fast_tanh(gg);
      h_sh[t] = fast_sigmoid(go) * fast_tanh(c);
    }
    sync_lds();
  }
}

// ---------------- K3: CRF forward scan + gold score, 1 thread per batch ------
// lse_i(a_i + tr_ji) = M + log(sum_i exp(a_i - M) * exp(tr_ji)); exp(tr) is
// uniform -> precomputed once. No cross-lane ops in the 512-step chain.
__global__ __launch_bounds__(64) void k_crf(
    const float* __restrict__ featsF, const float* __restrict__ featsB,
    const float* __restrict__ trans, const int* __restrict__ tags,
    float* __restrict__ out){
  __shared__ float tr_sh[40];
  const int lane = threadIdx.x;
  const int b = blockIdx.x * 64 + lane;
  if (lane < 36) tr_sh[lane] = trans[lane];
  __syncthreads();

  float T[6][6];
  #pragma unroll
  for (int j = 0; j < 6; ++j)
    #pragma unroll
    for (int i = 0; i < 6; ++i)
      T[j][i] = __expf(trans[j * 6 + i]);   // exp(NEG)=0 blocks transitions exactly
  float T5[6];
  #pragma unroll
  for (int j = 0; j < 6; ++j) T5[j] = trans[30 + j];

  float a[6];
  #pragma unroll
  for (int j = 0; j < 6; ++j) a[j] = NEGV;
  a[STARTT] = 0.f;

  const size_t ST = (size_t)BB * TT;
  const float* fF = featsF + (size_t)b * TT;
  const float* fB = featsB + (size_t)b * TT;

  float fc[6], fn[6];
  #pragma unroll
  for (int j = 0; j < 6; ++j){
    fc[j] = fF[j] + fB[j];
    fn[j] = fF[ST + j] + fB[ST + j];
  }

  const int* tg = tags + (size_t)b * SS;
  int tp = STARTT;
  int tc = tg[0], t1 = tg[1], t2n = tg[2];
  float gc = fF[tc] + fB[tc];
  float gn = fF[ST + t1] + fB[ST + t1];
  float gold = 0.f;

  for (int s = 0; s < SS; ++s){
    gold += gc + tr_sh[tc * 6 + tp];

    float M = fmaxf(fmaxf(fmaxf(a[0], a[1]), fmaxf(a[2], a[3])), fmaxf(a[4], a[5]));
    float e0 = __expf(a[0] - M), e1 = __expf(a[1] - M), e2 = __expf(a[2] - M),
          e3 = __expf(a[3] - M), e4 = __expf(a[4] - M), e5 = __expf(a[5] - M);
    #pragma unroll
    for (int j = 0; j < 6; ++j){
      float sj = e0 * T[j][0] + e1 * T[j][1] + e2 * T[j][2]
               + e3 * T[j][3] + e4 * T[j][4] + e5 * T[j][5];
      a[j] = M + __logf(sj) + fc[j];
    }
    #pragma unroll
    for (int j = 0; j < 6; ++j) fc[j] = fn[j];
    if (s + 2 < SS){
      #pragma unroll
      for (int j = 0; j < 6; ++j)
        fn[j] = fF[(size_t)(s + 2) * ST + j] + fB[(size_t)(s + 2) * ST + j];
    }
    tp = tc; tc = t1; t1 = t2n;
    t2n = (s + 3 < SS) ? tg[s + 3] : 0;
    gc = gn;
    gn = (s + 2 < SS) ? (fF[(size_t)(s + 2) * ST + t1] + fB[(size_t)(s + 2) * ST + t1]) : 0.f;
  }
  gold += tr_sh[STOPT * 6 + tp];

  float m2 = -1e30f;
  #pragma unroll
  for (int j = 0; j < 6; ++j) m2 = fmaxf(m2, a[j] + T5[j]);
  float ssum = 0.f;
  #pragma unroll
  for (int j = 0; j < 6; ++j) ssum += __expf(a[j] + T5[j] - m2);
  out[b] = m2 + __logf(ssum) - gold;
}

// ---------------- launch -----------------------------------------------------
extern "C" void kernel_launch(void* const* d_in, const int* in_sizes, int n_in,
                              void* d_out, int out_size, void* d_ws, size_t ws_size,
                              hipStream_t stream){
  const int*   sentence = (const int*)  d_in[0];
  const int*   tags     = (const int*)  d_in[1];
  const float* emb      = (const float*)d_in[2];
  const float* w_ih_f   = (const float*)d_in[3];
  const float* w_hh_f   = (const float*)d_in[4];
  const float* b_ih_f   = (const float*)d_in[5];
  const float* b_hh_f   = (const float*)d_in[6];
  const float* w_ih_b   = (const float*)d_in[7];
  const float* w_hh_b   = (const float*)d_in[8];
  const float* b_ih_b   = (const float*)d_in[9];
  const float* b_hh_b   = (const float*)d_in[10];
  const float* h0       = (const float*)d_in[11];
  const float* c0       = (const float*)d_in[12];
  const float* w_out    = (const float*)d_in[13];
  const float* b_out    = (const float*)d_in[14];
  const float* trans    = (const float*)d_in[15];
  float* out = (float*)d_out;

  float* ws = (float*)d_ws;
  float* vxg    = ws;                                 // [2][8000][300]
  float* embp   = vxg + (size_t)2 * VOCABN * G4;      // [8064][304]
  float* wp     = embp + (size_t)VP * EP;             // [2][320][304]
  float* featsF = wp + (size_t)2 * GP * EP;           // [512][256][6] (incl b_out)
  float* featsB = featsF + (size_t)SS * BB * TT;      // [512][256][6]

  k_prep<<<2048, 256, 0, stream>>>(emb, w_ih_f, w_ih_b, embp, wp);
  k_gemm<<<2 * 63 * 5, 256, 0, stream>>>(embp, wp, b_ih_f, b_hh_f, b_ih_b, b_hh_b, vxg);
  k_lstm<<<512, 192, 0, stream>>>(sentence, vxg, w_hh_f, w_hh_b, h0, c0, w_out, b_out,
                                  featsF, featsB);
  k_crf<<<4, 64, 0, stream>>>(featsF, featsB, trans, tags, out);
}

// Round 3
// 1132.963 us; speedup vs baseline: 1.4045x; 1.0055x over previous
//
#include <hip/hip_runtime.h>
#include <stdint.h>

#define VOCABN 8000
#define EE     300
#define HH     75
#define G4     300   // 4*H
#define TT     6
#define BB     256
#define SS     512
#define STARTT 4
#define STOPT  5
#define NEGV   (-10000.0f)

__device__ __forceinline__ float fast_sigmoid(float x){
  return __builtin_amdgcn_rcpf(1.0f + __expf(-x));
}
__device__ __forceinline__ float fast_tanh(float x){
  x = fminf(15.0f, fmaxf(-15.0f, x));
  float e = __expf(2.0f * x);
  return (e - 1.0f) * __builtin_amdgcn_rcpf(e + 1.0f);
}

// raw barrier: orders LDS (lgkmcnt) but does NOT drain vmcnt -> global
// prefetches stay in flight across steps (guide §5/§6 G15 pattern).
__device__ __forceinline__ void sync_lds(){
  __builtin_amdgcn_sched_barrier(0);
  asm volatile("s_waitcnt lgkmcnt(0)" ::: "memory");
  __builtin_amdgcn_s_barrier();
  __builtin_amdgcn_sched_barrier(0);
}

#define RL(x, l) __int_as_float(__builtin_amdgcn_readlane(__float_as_int(x), (l)))

// ---------------- K1: vocab_xg[dir][v][g] = emb[v] . w_ih[g] + b_ih[g]+b_hh[g]
// reads raw (unpadded) emb / w_ih; row-clamped loads + zeroed tail of the last
// K-chunk (E=300 = 18*16 + 12).
#define LDSR 20
__global__ __launch_bounds__(256) void k_gemm(
    const float* __restrict__ emb, const float* __restrict__ w_ih_f,
    const float* __restrict__ w_ih_b,
    const float* __restrict__ b_ih_f, const float* __restrict__ b_hh_f,
    const float* __restrict__ b_ih_b, const float* __restrict__ b_hh_b,
    float* __restrict__ vxg){
  __shared__ alignas(16) float a_sh[128 * LDSR];
  __shared__ alignas(16) float b_sh[64 * LDSR];
  __shared__ float bias_sh[64];
  const int bx = blockIdx.x;
  const int dir = bx / (63 * 5);
  const int rem = bx % (63 * 5);
  const int vt = rem / 5, gt = rem % 5;
  const int v0 = vt * 128, g0 = gt * 64;
  const int tid = threadIdx.x;
  const float* wdir = dir ? w_ih_b : w_ih_f;

  if (tid < 64){
    int g = g0 + tid;
    float bi = 0.f;
    if (g < G4) bi = dir ? (b_ih_b[g] + b_hh_b[g]) : (b_ih_f[g] + b_hh_f[g]);
    bias_sh[tid] = bi;
  }

  float acc[8][4];
  #pragma unroll
  for (int i = 0; i < 8; ++i)
    #pragma unroll
    for (int j = 0; j < 4; ++j) acc[i][j] = 0.f;

  const int tx = tid & 15, ty = tid >> 4;
  const int la_r = tid >> 1, la_h = (tid & 1) * 8;
  const int lb_r = tid >> 2, lb_h = (tid & 3) * 4;

  // row-clamped base pointers (OOB tile rows read row 0; outputs are guarded)
  const int va = v0 + la_r;
  const float* arow = emb + (size_t)(va < VOCABN ? va : 0) * EE;
  const int gb = g0 + lb_r;
  const float* brow = wdir + (size_t)(gb < G4 ? gb : 0) * EE;
  const float4 z4 = {0.f, 0.f, 0.f, 0.f};

  for (int kk = 0; kk < 19; ++kk){
    const int e0 = kk * 16;
    float4 av0 = *(const float4*)&arow[e0 + la_h];                 // cols always < 300
    float4 av1 = (e0 + la_h + 7 < EE) ? *(const float4*)&arow[e0 + la_h + 4] : z4;
    float4 bv  = (e0 + lb_h + 3 < EE) ? *(const float4*)&brow[e0 + lb_h]     : z4;
    __syncthreads();
    *(float4*)&a_sh[la_r * LDSR + la_h]     = av0;
    *(float4*)&a_sh[la_r * LDSR + la_h + 4] = av1;
    *(float4*)&b_sh[lb_r * LDSR + lb_h]     = bv;
    __syncthreads();
    #pragma unroll
    for (int e4 = 0; e4 < 4; ++e4){
      float4 bq[4], aq[8];
      #pragma unroll
      for (int j = 0; j < 4; ++j) bq[j] = *(const float4*)&b_sh[(tx + 16 * j) * LDSR + e4 * 4];
      #pragma unroll
      for (int i = 0; i < 8; ++i) aq[i] = *(const float4*)&a_sh[(ty + 16 * i) * LDSR + e4 * 4];
      #pragma unroll
      for (int i = 0; i < 8; ++i)
        #pragma unroll
        for (int j = 0; j < 4; ++j)
          acc[i][j] += aq[i].x * bq[j].x + aq[i].y * bq[j].y
                     + aq[i].z * bq[j].z + aq[i].w * bq[j].w;
    }
  }

  const size_t obase = (size_t)dir * VOCABN * G4;
  #pragma unroll
  for (int i = 0; i < 8; ++i){
    int v = v0 + ty + 16 * i;
    if (v < VOCABN){
      #pragma unroll
      for (int j = 0; j < 4; ++j){
        int g = g0 + tx + 16 * j;
        if (g < G4) vxg[obase + (size_t)v * G4 + g] = acc[i][j] + bias_sh[tx + 16 * j];
      }
    }
  }
}

// ---------------- K2: per-(dir,batch) LSTM recurrence, feats fused -----------
// 192 threads: t<150 -> gate rows t and t+150 (weights in VGPR — launch_bounds
// (192,1) lifts the register cap so the 152 weight floats do NOT spill);
// t in [150,156) -> one w_out feature row. h broadcast: 1 ds_read_b128/wave +
// v_readlane, FMAs take the h value as the SGPR operand.
__global__ __launch_bounds__(192, 1) void k_lstm(
    const int* __restrict__ sentence, const float* __restrict__ vxg,
    const float* __restrict__ w_hh_f, const float* __restrict__ w_hh_b,
    const float* __restrict__ h0, const float* __restrict__ c0,
    const float* __restrict__ w_out, const float* __restrict__ b_out,
    float* __restrict__ featsF, float* __restrict__ featsB){
  __shared__ alignas(16) float h_sh[256];
  __shared__ float gates_sh[G4];
  __shared__ int tok_sh[SS];
  const int bx = blockIdx.x;
  const int dir = bx >> 8;
  const int b = bx & 255;
  const int t = threadIdx.x;
  const int lane = t & 63;

  for (int i = t; i < SS; i += 192) tok_sh[i] = sentence[b * SS + i];

  float w0[76], w1[76];
  #pragma unroll
  for (int j = 0; j < 76; ++j){ w0[j] = 0.f; w1[j] = 0.f; }
  if (t < 150){
    const float* whh = dir ? w_hh_b : w_hh_f;
    #pragma unroll
    for (int j = 0; j < HH; ++j){
      w0[j] = whh[t * HH + j];
      w1[j] = whh[(t + 150) * HH + j];
    }
  } else if (t < 156){
    #pragma unroll
    for (int j = 0; j < HH; ++j)
      w0[j] = w_out[(t - 150) * (2 * HH) + dir * HH + j];
  }
  float c = 0.f;
  if (t < HH){
    c = c0[((size_t)dir * BB + b) * HH + t];
    h_sh[t] = h0[((size_t)dir * BB + b) * HH + t];
  }
  for (int i = t + HH; i < 256; i += 192) h_sh[i] = 0.f;  // pad lanes 19..63
  __syncthreads();

  const float* vx = vxg + (size_t)dir * VOCABN * G4;
  float* feats = dir ? featsB : featsF;

  float cur0 = 0.f, cur1 = 0.f, nx0 = 0.f, nx1 = 0.f;
  if (t < 150){
    int sA = dir ? (SS - 1) : 0;
    int sB = dir ? (SS - 2) : 1;
    cur0 = vx[(size_t)tok_sh[sA] * G4 + t];
    cur1 = vx[(size_t)tok_sh[sA] * G4 + t + 150];
    nx0  = vx[(size_t)tok_sh[sB] * G4 + t];
    nx1  = vx[(size_t)tok_sh[sB] * G4 + t + 150];
  } else if (t < 156 && dir == 0){
    cur0 = b_out[t - 150];  // bias folded into feature dot init
  }

  for (int k = 0; k <= SS; ++k){
    // ---- phase A: gate dots (step k) + feature dots (step k-1) ----
    float p0 = 0.f, p1 = 0.f;
    if (t < 150 && k + 2 < SS){
      int s2 = dir ? (SS - 3 - k) : (k + 2);
      int tok2 = tok_sh[s2];
      p0 = vx[(size_t)tok2 * G4 + t];          // depth-2 prefetch, survives the
      p1 = vx[(size_t)tok2 * G4 + t + 150];    // raw barriers (no vmcnt drain)
    }
    const float4 hv = *((const float4*)h_sh + lane);
    float a0 = cur0, a1 = 0.f, a2 = 0.f, a3 = 0.f;
    float d0 = cur1, d1 = 0.f, d2 = 0.f, d3 = 0.f;
    #pragma unroll
    for (int q = 0; q < 19; ++q){
      float e0 = RL(hv.x, q), e1 = RL(hv.y, q), e2 = RL(hv.z, q), e3 = RL(hv.w, q);
      a0 += e0 * w0[4 * q + 0];  d0 += e0 * w1[4 * q + 0];
      a1 += e1 * w0[4 * q + 1];  d1 += e1 * w1[4 * q + 1];
      a2 += e2 * w0[4 * q + 2];  d2 += e2 * w1[4 * q + 2];
      a3 += e3 * w0[4 * q + 3];  d3 += e3 * w1[4 * q + 3];
    }
    float r0 = (a0 + a1) + (a2 + a3);
    float r1 = (d0 + d1) + (d2 + d3);

    if (t < 150){
      if (k < SS){
        gates_sh[t] = r0;
        gates_sh[t + 150] = r1;
        cur0 = nx0; cur1 = nx1; nx0 = p0; nx1 = p1;
      }
    } else if (t < 156 && k > 0){
      int ps = dir ? (SS - k) : (k - 1);
      feats[((size_t)ps * BB + b) * TT + (t - 150)] = r0;
    }
    if (k == SS) break;
    sync_lds();
    // ---- phase B: activations (threads 0..74) ----
    if (t < HH){
      float gi = gates_sh[t];
      float gf = gates_sh[HH + t];
      float gg = gates_sh[2 * HH + t];
      float go = gates_sh[3 * HH + t];
      c = fast_sigmoid(gf) * c + fast_sigmoid(gi) * fast_tanh(gg);
      h_sh[t] = fast_sigmoid(go) * fast_tanh(c);
    }
    sync_lds();
  }
}

// ---------------- K3: CRF forward scan + gold score, 1 thread per batch ------
// lse_i(a_i + tr_ji) = M + log(sum_i exp(a_i - M) * exp(tr_ji)); exp(tr) is
// uniform -> precomputed once. No cross-lane ops in the 512-step chain.
__global__ __launch_bounds__(64) void k_crf(
    const float* __restrict__ featsF, const float* __restrict__ featsB,
    const float* __restrict__ trans, const int* __restrict__ tags,
    float* __restrict__ out){
  __shared__ float tr_sh[40];
  const int lane = threadIdx.x;
  const int b = blockIdx.x * 64 + lane;
  if (lane < 36) tr_sh[lane] = trans[lane];
  __syncthreads();

  float T[6][6];
  #pragma unroll
  for (int j = 0; j < 6; ++j)
    #pragma unroll
    for (int i = 0; i < 6; ++i)
      T[j][i] = __expf(trans[j * 6 + i]);   // exp(NEG)=0 blocks transitions exactly
  float T5[6];
  #pragma unroll
  for (int j = 0; j < 6; ++j) T5[j] = trans[30 + j];

  float a[6];
  #pragma unroll
  for (int j = 0; j < 6; ++j) a[j] = NEGV;
  a[STARTT] = 0.f;

  const size_t ST = (size_t)BB * TT;
  const float* fF = featsF + (size_t)b * TT;
  const float* fB = featsB + (size_t)b * TT;

  float fc[6], fn[6];
  #pragma unroll
  for (int j = 0; j < 6; ++j){
    fc[j] = fF[j] + fB[j];
    fn[j] = fF[ST + j] + fB[ST + j];
  }

  const int* tg = tags + (size_t)b * SS;
  int tp = STARTT;
  int tc = tg[0], t1 = tg[1], t2n = tg[2];
  float gc = fF[tc] + fB[tc];
  float gn = fF[ST + t1] + fB[ST + t1];
  float gold = 0.f;

  for (int s = 0; s < SS; ++s){
    gold += gc + tr_sh[tc * 6 + tp];

    float M = fmaxf(fmaxf(fmaxf(a[0], a[1]), fmaxf(a[2], a[3])), fmaxf(a[4], a[5]));
    float e0 = __expf(a[0] - M), e1 = __expf(a[1] - M), e2 = __expf(a[2] - M),
          e3 = __expf(a[3] - M), e4 = __expf(a[4] - M), e5 = __expf(a[5] - M);
    #pragma unroll
    for (int j = 0; j < 6; ++j){
      float sj = e0 * T[j][0] + e1 * T[j][1] + e2 * T[j][2]
               + e3 * T[j][3] + e4 * T[j][4] + e5 * T[j][5];
      a[j] = M + __logf(sj) + fc[j];
    }
    #pragma unroll
    for (int j = 0; j < 6; ++j) fc[j] = fn[j];
    if (s + 2 < SS){
      #pragma unroll
      for (int j = 0; j < 6; ++j)
        fn[j] = fF[(size_t)(s + 2) * ST + j] + fB[(size_t)(s + 2) * ST + j];
    }
    tp = tc; tc = t1; t1 = t2n;
    t2n = (s + 3 < SS) ? tg[s + 3] : 0;
    gc = gn;
    gn = (s + 2 < SS) ? (fF[(size_t)(s + 2) * ST + t1] + fB[(size_t)(s + 2) * ST + t1]) : 0.f;
  }
  gold += tr_sh[STOPT * 6 + tp];

  float m2 = -1e30f;
  #pragma unroll
  for (int j = 0; j < 6; ++j) m2 = fmaxf(m2, a[j] + T5[j]);
  float ssum = 0.f;
  #pragma unroll
  for (int j = 0; j < 6; ++j) ssum += __expf(a[j] + T5[j] - m2);
  out[b] = m2 + __logf(ssum) - gold;
}

// ---------------- launch -----------------------------------------------------
extern "C" void kernel_launch(void* const* d_in, const int* in_sizes, int n_in,
                              void* d_out, int out_size, void* d_ws, size_t ws_size,
                              hipStream_t stream){
  const int*   sentence = (const int*)  d_in[0];
  const int*   tags     = (const int*)  d_in[1];
  const float* emb      = (const float*)d_in[2];
  const float* w_ih_f   = (const float*)d_in[3];
  const float* w_hh_f   = (const float*)d_in[4];
  const float* b_ih_f   = (const float*)d_in[5];
  const float* b_hh_f   = (const float*)d_in[6];
  const float* w_ih_b   = (const float*)d_in[7];
  const float* w_hh_b   = (const float*)d_in[8];
  const float* b_ih_b   = (const float*)d_in[9];
  const float* b_hh_b   = (const float*)d_in[10];
  const float* h0       = (const float*)d_in[11];
  const float* c0       = (const float*)d_in[12];
  const float* w_out    = (const float*)d_in[13];
  const float* b_out    = (const float*)d_in[14];
  const float* trans    = (const float*)d_in[15];
  float* out = (float*)d_out;

  float* ws = (float*)d_ws;
  float* vxg    = ws;                                 // [2][8000][300]
  float* featsF = vxg + (size_t)2 * VOCABN * G4;      // [512][256][6] (incl b_out)
  float* featsB = featsF + (size_t)SS * BB * TT;      // [512][256][6]

  k_gemm<<<2 * 63 * 5, 256, 0, stream>>>(emb, w_ih_f, w_ih_b,
                                         b_ih_f, b_hh_f, b_ih_b, b_hh_b, vxg);
  k_lstm<<<512, 192, 0, stream>>>(sentence, vxg, w_hh_f, w_hh_b, h0, c0, w_out, b_out,
                                  featsF, featsB);
  k_crf<<<4, 64, 0, stream>>>(featsF, featsB, trans, tags, out);
}

// Round 4
// 1111.715 us; speedup vs baseline: 1.4313x; 1.0191x over previous
//
#include <hip/hip_runtime.h>
#include <stdint.h>

#define VOCABN 8000
#define EE     300
#define HH     75
#define G4     300   // 4*H
#define TT     6
#define BB     256
#define SS     512
#define STARTT 4
#define STOPT  5
#define NEGV   (-10000.0f)

typedef float f32x16 __attribute__((ext_vector_type(16)));

__device__ __forceinline__ float fast_sigmoid(float x){
  return __builtin_amdgcn_rcpf(1.0f + __expf(-x));
}
__device__ __forceinline__ float fast_tanh(float x){
  x = fminf(15.0f, fmaxf(-15.0f, x));
  float e = __expf(2.0f * x);
  return (e - 1.0f) * __builtin_amdgcn_rcpf(e + 1.0f);
}

// raw barrier: orders LDS (lgkmcnt) but does NOT drain vmcnt -> global
// prefetches stay in flight across steps (guide §5/§6 G15 pattern).
__device__ __forceinline__ void sync_lds(){
  __builtin_amdgcn_sched_barrier(0);
  asm volatile("s_waitcnt lgkmcnt(0)" ::: "memory");
  __builtin_amdgcn_s_barrier();
  __builtin_amdgcn_sched_barrier(0);
}

#define RL(x, l) __int_as_float(__builtin_amdgcn_readlane(__float_as_int(x), (l)))

// ---------------- K1: vocab_xg[dir][v][g] = emb[v] . w_ih[g] + b_ih[g]+b_hh[g]
#define LDSR 20
__global__ __launch_bounds__(256) void k_gemm(
    const float* __restrict__ emb, const float* __restrict__ w_ih_f,
    const float* __restrict__ w_ih_b,
    const float* __restrict__ b_ih_f, const float* __restrict__ b_hh_f,
    const float* __restrict__ b_ih_b, const float* __restrict__ b_hh_b,
    float* __restrict__ vxg){
  __shared__ alignas(16) float a_sh[128 * LDSR];
  __shared__ alignas(16) float b_sh[64 * LDSR];
  __shared__ float bias_sh[64];
  const int bx = blockIdx.x;
  const int dir = bx / (63 * 5);
  const int rem = bx % (63 * 5);
  const int vt = rem / 5, gt = rem % 5;
  const int v0 = vt * 128, g0 = gt * 64;
  const int tid = threadIdx.x;
  const float* wdir = dir ? w_ih_b : w_ih_f;

  if (tid < 64){
    int g = g0 + tid;
    float bi = 0.f;
    if (g < G4) bi = dir ? (b_ih_b[g] + b_hh_b[g]) : (b_ih_f[g] + b_hh_f[g]);
    bias_sh[tid] = bi;
  }

  float acc[8][4];
  #pragma unroll
  for (int i = 0; i < 8; ++i)
    #pragma unroll
    for (int j = 0; j < 4; ++j) acc[i][j] = 0.f;

  const int tx = tid & 15, ty = tid >> 4;
  const int la_r = tid >> 1, la_h = (tid & 1) * 8;
  const int lb_r = tid >> 2, lb_h = (tid & 3) * 4;

  const int va = v0 + la_r;
  const float* arow = emb + (size_t)(va < VOCABN ? va : 0) * EE;
  const int gb = g0 + lb_r;
  const float* brow = wdir + (size_t)(gb < G4 ? gb : 0) * EE;
  const float4 z4 = {0.f, 0.f, 0.f, 0.f};

  for (int kk = 0; kk < 19; ++kk){
    const int e0 = kk * 16;
    float4 av0 = *(const float4*)&arow[e0 + la_h];
    float4 av1 = (e0 + la_h + 7 < EE) ? *(const float4*)&arow[e0 + la_h + 4] : z4;
    float4 bv  = (e0 + lb_h + 3 < EE) ? *(const float4*)&brow[e0 + lb_h]     : z4;
    __syncthreads();
    *(float4*)&a_sh[la_r * LDSR + la_h]     = av0;
    *(float4*)&a_sh[la_r * LDSR + la_h + 4] = av1;
    *(float4*)&b_sh[lb_r * LDSR + lb_h]     = bv;
    __syncthreads();
    #pragma unroll
    for (int e4 = 0; e4 < 4; ++e4){
      float4 bq[4], aq[8];
      #pragma unroll
      for (int j = 0; j < 4; ++j) bq[j] = *(const float4*)&b_sh[(tx + 16 * j) * LDSR + e4 * 4];
      #pragma unroll
      for (int i = 0; i < 8; ++i) aq[i] = *(const float4*)&a_sh[(ty + 16 * i) * LDSR + e4 * 4];
      #pragma unroll
      for (int i = 0; i < 8; ++i)
        #pragma unroll
        for (int j = 0; j < 4; ++j)
          acc[i][j] += aq[i].x * bq[j].x + aq[i].y * bq[j].y
                     + aq[i].z * bq[j].z + aq[i].w * bq[j].w;
    }
  }

  const size_t obase = (size_t)dir * VOCABN * G4;
  #pragma unroll
  for (int i = 0; i < 8; ++i){
    int v = v0 + ty + 16 * i;
    if (v < VOCABN){
      #pragma unroll
      for (int j = 0; j < 4; ++j){
        int g = g0 + tx + 16 * j;
        if (g < G4) vxg[obase + (size_t)v * G4 + g] = acc[i][j] + bias_sh[tx + 16 * j];
      }
    }
  }
}

// ---------------- K2: per-(dir,batch) LSTM recurrence, feats fused -----------
// Weights live in NAMED f32x16 vectors (no allocas -> no scratch demotion),
// pinned with an asm liveness barrier so the compiler cannot sink the loads
// back into the 512-step loop (round-3 finding: array form re-streamed 23.6 TB
// through L2 = the whole 675 us).
#define SETW(W0,W1,W2,W3,W4,j,val) do{ \
  if ((j) < 16) (W0)[(j)&15] = (val); \
  else if ((j) < 32) (W1)[(j)&15] = (val); \
  else if ((j) < 48) (W2)[(j)&15] = (val); \
  else if ((j) < 64) (W3)[(j)&15] = (val); \
  else (W4)[(j)&15] = (val); }while(0)
#define GETW(W0,W1,W2,W3,W4,j) \
  ((j) < 16 ? (W0)[(j)&15] : (j) < 32 ? (W1)[(j)&15] : (j) < 48 ? (W2)[(j)&15] : \
   (j) < 64 ? (W3)[(j)&15] : (W4)[(j)&15])

__global__ __launch_bounds__(192, 1) void k_lstm(
    const int* __restrict__ sentence, const float* __restrict__ vxg,
    const float* __restrict__ w_hh_f, const float* __restrict__ w_hh_b,
    const float* __restrict__ h0, const float* __restrict__ c0,
    const float* __restrict__ w_out, const float* __restrict__ b_out,
    float* __restrict__ featsF, float* __restrict__ featsB){
  __shared__ alignas(16) float h_sh[256];
  __shared__ float gates_sh[G4];
  __shared__ int tok_sh[SS];
  const int dir = blockIdx.x >> 8;
  const int b = blockIdx.x & 255;
  const int t = threadIdx.x;
  const int lane = t & 63;

  for (int i = t; i < SS; i += 192) tok_sh[i] = sentence[b * SS + i];

  f32x16 wA0, wA1, wA2, wA3, wA4, wB0, wB1, wB2, wB3, wB4;
  #pragma unroll
  for (int j = 0; j < 16; ++j){
    wA0[j] = 0.f; wA1[j] = 0.f; wA2[j] = 0.f; wA3[j] = 0.f; wA4[j] = 0.f;
    wB0[j] = 0.f; wB1[j] = 0.f; wB2[j] = 0.f; wB3[j] = 0.f; wB4[j] = 0.f;
  }
  if (t < 150){
    const float* whh = dir ? w_hh_b : w_hh_f;
    const float* r0 = whh + t * HH;
    const float* r1 = whh + (t + 150) * HH;
    #pragma unroll
    for (int j = 0; j < HH; ++j){
      SETW(wA0, wA1, wA2, wA3, wA4, j, r0[j]);
      SETW(wB0, wB1, wB2, wB3, wB4, j, r1[j]);
    }
  } else if (t < 156){
    const float* r0 = w_out + (t - 150) * (2 * HH) + dir * HH;
    #pragma unroll
    for (int j = 0; j < HH; ++j) SETW(wA0, wA1, wA2, wA3, wA4, j, r0[j]);
  }
  asm volatile("" : "+v"(wA0), "+v"(wA1), "+v"(wA2), "+v"(wA3), "+v"(wA4),
                    "+v"(wB0), "+v"(wB1), "+v"(wB2), "+v"(wB3), "+v"(wB4));

  float c = 0.f;
  if (t < HH){
    c = c0[((size_t)dir * BB + b) * HH + t];
    h_sh[t] = h0[((size_t)dir * BB + b) * HH + t];
  }
  for (int i = t + HH; i < 256; i += 192) h_sh[i] = 0.f;  // pad lanes 19..63
  __syncthreads();

  const float* vx = vxg + (size_t)dir * VOCABN * G4;
  float* feats = dir ? featsB : featsF;

  float cur0 = 0.f, cur1 = 0.f, nx0 = 0.f, nx1 = 0.f;
  if (t < 150){
    int sA = dir ? (SS - 1) : 0;
    int sB = dir ? (SS - 2) : 1;
    cur0 = vx[(size_t)tok_sh[sA] * G4 + t];
    cur1 = vx[(size_t)tok_sh[sA] * G4 + t + 150];
    nx0  = vx[(size_t)tok_sh[sB] * G4 + t];
    nx1  = vx[(size_t)tok_sh[sB] * G4 + t + 150];
  } else if (t < 156 && dir == 0){
    cur0 = b_out[t - 150];  // bias folded into feature dot init
  }

  for (int k = 0; k <= SS; ++k){
    // ---- phase A: gate dots (step k) + feature dots (step k-1) ----
    float p0 = 0.f, p1 = 0.f;
    if (t < 150 && k + 2 < SS){
      int s2 = dir ? (SS - 3 - k) : (k + 2);
      int tok2 = tok_sh[s2];
      p0 = vx[(size_t)tok2 * G4 + t];          // depth-2 prefetch, survives the
      p1 = vx[(size_t)tok2 * G4 + t + 150];    // raw barriers (no vmcnt drain)
    }
    const float4 hv = *((const float4*)h_sh + lane);
    float a0 = cur0, a1 = 0.f, a2 = 0.f, a3 = 0.f;
    float d0 = cur1, d1 = 0.f, d2 = 0.f, d3 = 0.f;
    #pragma unroll
    for (int q = 0; q < 19; ++q){
      float e0 = RL(hv.x, q), e1 = RL(hv.y, q), e2 = RL(hv.z, q), e3 = RL(hv.w, q);
      a0 += e0 * GETW(wA0, wA1, wA2, wA3, wA4, 4 * q + 0);
      d0 += e0 * GETW(wB0, wB1, wB2, wB3, wB4, 4 * q + 0);
      a1 += e1 * GETW(wA0, wA1, wA2, wA3, wA4, 4 * q + 1);
      d1 += e1 * GETW(wB0, wB1, wB2, wB3, wB4, 4 * q + 1);
      a2 += e2 * GETW(wA0, wA1, wA2, wA3, wA4, 4 * q + 2);
      d2 += e2 * GETW(wB0, wB1, wB2, wB3, wB4, 4 * q + 2);
      a3 += e3 * GETW(wA0, wA1, wA2, wA3, wA4, 4 * q + 3);
      d3 += e3 * GETW(wB0, wB1, wB2, wB3, wB4, 4 * q + 3);
    }
    float r0 = (a0 + a1) + (a2 + a3);
    float r1 = (d0 + d1) + (d2 + d3);

    if (t < 150){
      if (k < SS){
        gates_sh[t] = r0;
        gates_sh[t + 150] = r1;
        cur0 = nx0; cur1 = nx1; nx0 = p0; nx1 = p1;
      }
    } else if (t < 156 && k > 0){
      int ps = dir ? (SS - k) : (k - 1);
      feats[((size_t)ps * BB + b) * TT + (t - 150)] = r0;
    }
    if (k == SS) break;
    sync_lds();
    // ---- phase B: activations (threads 0..74) ----
    if (t < HH){
      float gi = gates_sh[t];
      float gf = gates_sh[HH + t];
      float gg = gates_sh[2 * HH + t];
      float go = gates_sh[3 * HH + t];
      c = fast_sigmoid(gf) * c + fast_sigmoid(gi) * fast_tanh(gg);
      h_sh[t] = fast_sigmoid(go) * fast_tanh(c);
    }
    sync_lds();
  }
}

// ---------------- K3: CRF forward scan + gold score, 1 thread per batch ------
// Everything in NAMED scalars (no arrays -> no scratch). Tags staged once into
// LDS as swizzled packed u32 (1 ds_read per 4 steps). Gold transition/emit
// terms via cndmask select trees (tags are only 0..3 by construction).
#define TAGW(g) tag4_sh[(g) * 64 + ((lane + (g)) & 63)]

#define LOADSTAGE(X0,X1,X2,Y0,Y1,Y2, srow) do{ \
  int _r = (srow); if (_r >= SS) _r = 0; \
  const float2* _pF = (const float2*)(featsF + ((size_t)_r * BB + b) * TT); \
  const float2* _pB = (const float2*)(featsB + ((size_t)_r * BB + b) * TT); \
  X0 = _pF[0]; X1 = _pF[1]; X2 = _pF[2]; \
  Y0 = _pB[0]; Y1 = _pB[1]; Y2 = _pB[2]; }while(0)

#define CSTEP(X0,X1,X2,Y0,Y1,Y2, tcn, srow) do{ \
  float F0 = X0.x + Y0.x, F1 = X0.y + Y0.y, F2 = X1.x + Y1.x; \
  float F3 = X1.y + Y1.y, F4 = X2.x + Y2.x, F5 = X2.y + Y2.y; \
  /* gold: emit + trans[tcn][tp] via select trees */ \
  float em = (tcn)==0 ? F0 : (tcn)==1 ? F1 : (tcn)==2 ? F2 : F3; \
  float c0s = tp==0?g00:tp==1?g01:tp==2?g02:tp==3?g03:g04; \
  float c1s = tp==0?g10:tp==1?g11:tp==2?g12:tp==3?g13:g14; \
  float c2s = tp==0?g20:tp==1?g21:tp==2?g22:tp==3?g23:g24; \
  float c3s = tp==0?g30:tp==1?g31:tp==2?g32:tp==3?g33:g34; \
  gold += em + ((tcn)==0?c0s:(tcn)==1?c1s:(tcn)==2?c2s:c3s); \
  tp = (tcn); \
  /* alpha update: a_j = M + log(sum_i exp(a_i-M)*exp(tr_ji)) + F_j */ \
  float M = fmaxf(fmaxf(fmaxf(a0,a1),fmaxf(a2,a3)),fmaxf(a4,a5)); \
  float e0 = __expf(a0-M), e1 = __expf(a1-M), e2 = __expf(a2-M); \
  float e3 = __expf(a3-M), e4 = __expf(a4-M), e5 = __expf(a5-M); \
  float s0 = e0*T00+e1*T01+e2*T02+e3*T03+e4*T04+e5*T05; \
  float s1 = e0*T10+e1*T11+e2*T12+e3*T13+e4*T14+e5*T15; \
  float s2 = e0*T20+e1*T21+e2*T22+e3*T23+e4*T24+e5*T25; \
  float s3 = e0*T30+e1*T31+e2*T32+e3*T33+e4*T34+e5*T35; \
  float s4 = e0*T40+e1*T41+e2*T42+e3*T43+e4*T44+e5*T45; \
  float s5 = e0*T50+e1*T51+e2*T52+e3*T53+e4*T54+e5*T55; \
  a0 = M + __logf(s0) + F0;  a1 = M + __logf(s1) + F1; \
  a2 = M + __logf(s2) + F2;  a3 = M + __logf(s3) + F3; \
  a4 = M + __logf(s4) + F4;  a5 = M + __logf(s5) + F5; \
  LOADSTAGE(X0,X1,X2,Y0,Y1,Y2, (srow) + 4); }while(0)

__global__ __launch_bounds__(64, 1) void k_crf(
    const float* __restrict__ featsF, const float* __restrict__ featsB,
    const float* __restrict__ trans, const int* __restrict__ tags,
    float* __restrict__ out){
  __shared__ unsigned int tag4_sh[128 * 64];  // [s/4][swizzled lane] packed tags
  const int lane = threadIdx.x;
  const int b = blockIdx.x * 64 + lane;

  // stage tags: coalesced int4 global reads -> swizzled packed LDS words
  const int* tgblk = tags + (size_t)blockIdx.x * 64 * SS;
  for (int r = lane; r < 64 * 128; r += 64){
    int bi = r >> 7;        // batch-within-block 0..63
    int jj = r & 127;       // 4-step group 0..127
    int4 tv = ((const int4*)tgblk)[bi * 128 + jj];
    tag4_sh[jj * 64 + ((bi + jj) & 63)] =
        (unsigned)(tv.x & 255) | ((unsigned)(tv.y & 255) << 8) |
        ((unsigned)(tv.z & 255) << 16) | ((unsigned)(tv.w & 255) << 24);
  }
  __syncthreads();

  // exp(trans) matrix + gold transition entries, all named scalars
  float T00=__expf(trans[0]),  T01=__expf(trans[1]),  T02=__expf(trans[2]),  T03=__expf(trans[3]),  T04=__expf(trans[4]),  T05=__expf(trans[5]);
  float T10=__expf(trans[6]),  T11=__expf(trans[7]),  T12=__expf(trans[8]),  T13=__expf(trans[9]),  T14=__expf(trans[10]), T15=__expf(trans[11]);
  float T20=__expf(trans[12]), T21=__expf(trans[13]), T22=__expf(trans[14]), T23=__expf(trans[15]), T24=__expf(trans[16]), T25=__expf(trans[17]);
  float T30=__expf(trans[18]), T31=__expf(trans[19]), T32=__expf(trans[20]), T33=__expf(trans[21]), T34=__expf(trans[22]), T35=__expf(trans[23]);
  float T40=__expf(trans[24]), T41=__expf(trans[25]), T42=__expf(trans[26]), T43=__expf(trans[27]), T44=__expf(trans[28]), T45=__expf(trans[29]);
  float T50=__expf(trans[30]), T51=__expf(trans[31]), T52=__expf(trans[32]), T53=__expf(trans[33]), T54=__expf(trans[34]), T55=__expf(trans[35]);
  float g00=trans[0],  g01=trans[1],  g02=trans[2],  g03=trans[3],  g04=trans[4];
  float g10=trans[6],  g11=trans[7],  g12=trans[8],  g13=trans[9],  g14=trans[10];
  float g20=trans[12], g21=trans[13], g22=trans[14], g23=trans[15], g24=trans[16];
  float g30=trans[18], g31=trans[19], g32=trans[20], g33=trans[21], g34=trans[22];
  float g50=trans[30], g51=trans[31], g52=trans[32], g53=trans[33];
  float t54=trans[34], t55=trans[35];

  float a0 = NEGV, a1 = NEGV, a2 = NEGV, a3 = NEGV, a4 = 0.f, a5 = NEGV;
  float gold = 0.f;
  int tp = STARTT;

  float2 xA0,xA1,xA2,yA0,yA1,yA2, xB0,xB1,xB2,yB0,yB1,yB2;
  float2 xC0,xC1,xC2,yC0,yC1,yC2, xD0,xD1,xD2,yD0,yD1,yD2;
  LOADSTAGE(xA0,xA1,xA2,yA0,yA1,yA2, 0);
  LOADSTAGE(xB0,xB1,xB2,yB0,yB1,yB2, 1);
  LOADSTAGE(xC0,xC1,xC2,yC0,yC1,yC2, 2);
  LOADSTAGE(xD0,xD1,xD2,yD0,yD1,yD2, 3);

  unsigned twc = TAGW(0), twn = TAGW(1);
  for (int g = 0; g < 128; ++g){
    unsigned twp = TAGW(g + 2 < 128 ? g + 2 : 0);
    int u0 = twc & 255, u1 = (twc >> 8) & 255, u2 = (twc >> 16) & 255, u3 = twc >> 24;
    int sb = g * 4;
    CSTEP(xA0,xA1,xA2,yA0,yA1,yA2, u0, sb + 0);
    CSTEP(xB0,xB1,xB2,yB0,yB1,yB2, u1, sb + 1);
    CSTEP(xC0,xC1,xC2,yC0,yC1,yC2, u2, sb + 2);
    CSTEP(xD0,xD1,xD2,yD0,yD1,yD2, u3, sb + 3);
    twc = twn; twn = twp;
  }
  gold += (tp==0) ? g50 : (tp==1) ? g51 : (tp==2) ? g52 : g53;  // STOP <- last

  float z0 = a0 + g50, z1 = a1 + g51, z2 = a2 + g52;
  float z3 = a3 + g53, z4 = a4 + t54, z5 = a5 + t55;
  float M2 = fmaxf(fmaxf(fmaxf(z0,z1),fmaxf(z2,z3)),fmaxf(z4,z5));
  float ss = __expf(z0-M2)+__expf(z1-M2)+__expf(z2-M2)
           + __expf(z3-M2)+__expf(z4-M2)+__expf(z5-M2);
  out[b] = M2 + __logf(ss) - gold;
}

// ---------------- launch -----------------------------------------------------
extern "C" void kernel_launch(void* const* d_in, const int* in_sizes, int n_in,
                              void* d_out, int out_size, void* d_ws, size_t ws_size,
                              hipStream_t stream){
  const int*   sentence = (const int*)  d_in[0];
  const int*   tags     = (const int*)  d_in[1];
  const float* emb      = (const float*)d_in[2];
  const float* w_ih_f   = (const float*)d_in[3];
  const float* w_hh_f   = (const float*)d_in[4];
  const float* b_ih_f   = (const float*)d_in[5];
  const float* b_hh_f   = (const float*)d_in[6];
  const float* w_ih_b   = (const float*)d_in[7];
  const float* w_hh_b   = (const float*)d_in[8];
  const float* b_ih_b   = (const float*)d_in[9];
  const float* b_hh_b   = (const float*)d_in[10];
  const float* h0       = (const float*)d_in[11];
  const float* c0       = (const float*)d_in[12];
  const float* w_out    = (const float*)d_in[13];
  const float* b_out    = (const float*)d_in[14];
  const float* trans    = (const float*)d_in[15];
  float* out = (float*)d_out;

  float* ws = (float*)d_ws;
  float* vxg    = ws;                                 // [2][8000][300]
  float* featsF = vxg + (size_t)2 * VOCABN * G4;      // [512][256][6] (incl b_out)
  float* featsB = featsF + (size_t)SS * BB * TT;      // [512][256][6]

  k_gemm<<<2 * 63 * 5, 256, 0, stream>>>(emb, w_ih_f, w_ih_b,
                                         b_ih_f, b_hh_f, b_ih_b, b_hh_b, vxg);
  k_lstm<<<512, 192, 0, stream>>>(sentence, vxg, w_hh_f, w_hh_b, h0, c0, w_out, b_out,
                                  featsF, featsB);
  k_crf<<<BB / 64, 64, 0, stream>>>(featsF, featsB, trans, tags, out);
}

// Round 5
// 1108.822 us; speedup vs baseline: 1.4351x; 1.0026x over previous
//
#include <hip/hip_runtime.h>
#include <stdint.h>

#define VOCABN 8000
#define EE     300
#define HH     75
#define G4     300   // 4*H
#define TT     6
#define BB     256
#define SS     512
#define STARTT 4
#define STOPT  5
#define NEGV   (-10000.0f)

typedef float f32x16 __attribute__((ext_vector_type(16)));

__device__ __forceinline__ float fast_sigmoid(float x){
  return __builtin_amdgcn_rcpf(1.0f + __expf(-x));
}
__device__ __forceinline__ float fast_tanh(float x){
  x = fminf(15.0f, fmaxf(-15.0f, x));
  float e = __expf(2.0f * x);
  return (e - 1.0f) * __builtin_amdgcn_rcpf(e + 1.0f);
}

// raw barrier: orders LDS (lgkmcnt) but does NOT drain vmcnt -> global
// prefetches stay in flight across steps (guide §5/§6 G15 pattern).
__device__ __forceinline__ void sync_lds(){
  __builtin_amdgcn_sched_barrier(0);
  asm volatile("s_waitcnt lgkmcnt(0)" ::: "memory");
  __builtin_amdgcn_s_barrier();
  __builtin_amdgcn_sched_barrier(0);
}

#define RL(x, l) __int_as_float(__builtin_amdgcn_readlane(__float_as_int(x), (l)))

// ---------------- K1: vocab_xg[dir][v][g] = emb[v] . w_ih[g] + b_ih[g]+b_hh[g]
#define LDSR 20
__global__ __launch_bounds__(256) void k_gemm(
    const float* __restrict__ emb, const float* __restrict__ w_ih_f,
    const float* __restrict__ w_ih_b,
    const float* __restrict__ b_ih_f, const float* __restrict__ b_hh_f,
    const float* __restrict__ b_ih_b, const float* __restrict__ b_hh_b,
    float* __restrict__ vxg){
  __shared__ alignas(16) float a_sh[128 * LDSR];
  __shared__ alignas(16) float b_sh[64 * LDSR];
  __shared__ float bias_sh[64];
  const int bx = blockIdx.x;
  const int dir = bx / (63 * 5);
  const int rem = bx % (63 * 5);
  const int vt = rem / 5, gt = rem % 5;
  const int v0 = vt * 128, g0 = gt * 64;
  const int tid = threadIdx.x;
  const float* wdir = dir ? w_ih_b : w_ih_f;

  if (tid < 64){
    int g = g0 + tid;
    float bi = 0.f;
    if (g < G4) bi = dir ? (b_ih_b[g] + b_hh_b[g]) : (b_ih_f[g] + b_hh_f[g]);
    bias_sh[tid] = bi;
  }

  float acc[8][4];
  #pragma unroll
  for (int i = 0; i < 8; ++i)
    #pragma unroll
    for (int j = 0; j < 4; ++j) acc[i][j] = 0.f;

  const int tx = tid & 15, ty = tid >> 4;
  const int la_r = tid >> 1, la_h = (tid & 1) * 8;
  const int lb_r = tid >> 2, lb_h = (tid & 3) * 4;

  const int va = v0 + la_r;
  const float* arow = emb + (size_t)(va < VOCABN ? va : 0) * EE;
  const int gb = g0 + lb_r;
  const float* brow = wdir + (size_t)(gb < G4 ? gb : 0) * EE;
  const float4 z4 = {0.f, 0.f, 0.f, 0.f};

  for (int kk = 0; kk < 19; ++kk){
    const int e0 = kk * 16;
    float4 av0 = *(const float4*)&arow[e0 + la_h];
    float4 av1 = (e0 + la_h + 7 < EE) ? *(const float4*)&arow[e0 + la_h + 4] : z4;
    float4 bv  = (e0 + lb_h + 3 < EE) ? *(const float4*)&brow[e0 + lb_h]     : z4;
    __syncthreads();
    *(float4*)&a_sh[la_r * LDSR + la_h]     = av0;
    *(float4*)&a_sh[la_r * LDSR + la_h + 4] = av1;
    *(float4*)&b_sh[lb_r * LDSR + lb_h]     = bv;
    __syncthreads();
    #pragma unroll
    for (int e4 = 0; e4 < 4; ++e4){
      float4 bq[4], aq[8];
      #pragma unroll
      for (int j = 0; j < 4; ++j) bq[j] = *(const float4*)&b_sh[(tx + 16 * j) * LDSR + e4 * 4];
      #pragma unroll
      for (int i = 0; i < 8; ++i) aq[i] = *(const float4*)&a_sh[(ty + 16 * i) * LDSR + e4 * 4];
      #pragma unroll
      for (int i = 0; i < 8; ++i)
        #pragma unroll
        for (int j = 0; j < 4; ++j)
          acc[i][j] += aq[i].x * bq[j].x + aq[i].y * bq[j].y
                     + aq[i].z * bq[j].z + aq[i].w * bq[j].w;
    }
  }

  const size_t obase = (size_t)dir * VOCABN * G4;
  #pragma unroll
  for (int i = 0; i < 8; ++i){
    int v = v0 + ty + 16 * i;
    if (v < VOCABN){
      #pragma unroll
      for (int j = 0; j < 4; ++j){
        int g = g0 + tx + 16 * j;
        if (g < G4) vxg[obase + (size_t)v * G4 + g] = acc[i][j] + bias_sh[tx + 16 * j];
      }
    }
  }
}

// ---------------- K2: per-(dir,batch) LSTM recurrence, feats fused -----------
// Weights in NAMED f32x16 SSA vectors + asm pin. amdgpu_waves_per_eu(1,2)
// raises the scheduler/RA register budget to 256/wave (round-4 finding:
// launch_bounds' 2nd arg defaults to 1 -> no-op; default occupancy target
// capped the budget at ~88 and spilled the weights -> 23.6 TB L2 stream).
#define SETW(W0,W1,W2,W3,W4,j,val) do{ \
  if ((j) < 16) (W0)[(j)&15] = (val); \
  else if ((j) < 32) (W1)[(j)&15] = (val); \
  else if ((j) < 48) (W2)[(j)&15] = (val); \
  else if ((j) < 64) (W3)[(j)&15] = (val); \
  else (W4)[(j)&15] = (val); }while(0)
#define GETW(W0,W1,W2,W3,W4,j) \
  ((j) < 16 ? (W0)[(j)&15] : (j) < 32 ? (W1)[(j)&15] : (j) < 48 ? (W2)[(j)&15] : \
   (j) < 64 ? (W3)[(j)&15] : (W4)[(j)&15])

__global__ __launch_bounds__(192)
__attribute__((amdgpu_waves_per_eu(1, 2)))
void k_lstm(
    const int* __restrict__ sentence, const float* __restrict__ vxg,
    const float* __restrict__ w_hh_f, const float* __restrict__ w_hh_b,
    const float* __restrict__ h0, const float* __restrict__ c0,
    const float* __restrict__ w_out, const float* __restrict__ b_out,
    float* __restrict__ featsF, float* __restrict__ featsB){
  __shared__ alignas(16) float h_sh[256];
  __shared__ float gates_sh[G4];
  __shared__ int tok_sh[SS];
  const int dir = blockIdx.x >> 8;
  const int b = blockIdx.x & 255;
  const int t = threadIdx.x;
  const int lane = t & 63;

  for (int i = t; i < SS; i += 192) tok_sh[i] = sentence[b * SS + i];

  f32x16 wA0, wA1, wA2, wA3, wA4, wB0, wB1, wB2, wB3, wB4;
  #pragma unroll
  for (int j = 0; j < 16; ++j){
    wA0[j] = 0.f; wA1[j] = 0.f; wA2[j] = 0.f; wA3[j] = 0.f; wA4[j] = 0.f;
    wB0[j] = 0.f; wB1[j] = 0.f; wB2[j] = 0.f; wB3[j] = 0.f; wB4[j] = 0.f;
  }
  if (t < 150){
    const float* whh = dir ? w_hh_b : w_hh_f;
    const float* r0 = whh + t * HH;
    const float* r1 = whh + (t + 150) * HH;
    #pragma unroll
    for (int j = 0; j < HH; ++j){
      SETW(wA0, wA1, wA2, wA3, wA4, j, r0[j]);
      SETW(wB0, wB1, wB2, wB3, wB4, j, r1[j]);
    }
  } else if (t < 156){
    const float* r0 = w_out + (t - 150) * (2 * HH) + dir * HH;
    #pragma unroll
    for (int j = 0; j < HH; ++j) SETW(wA0, wA1, wA2, wA3, wA4, j, r0[j]);
  }
  asm volatile("" : "+v"(wA0), "+v"(wA1), "+v"(wA2), "+v"(wA3), "+v"(wA4),
                    "+v"(wB0), "+v"(wB1), "+v"(wB2), "+v"(wB3), "+v"(wB4));

  float c = 0.f;
  if (t < HH){
    c = c0[((size_t)dir * BB + b) * HH + t];
    h_sh[t] = h0[((size_t)dir * BB + b) * HH + t];
  }
  for (int i = t + HH; i < 256; i += 192) h_sh[i] = 0.f;  // pad lanes 19..63
  __syncthreads();

  const float* vx = vxg + (size_t)dir * VOCABN * G4;
  float* feats = dir ? featsB : featsF;

  float cur0 = 0.f, cur1 = 0.f, nx0 = 0.f, nx1 = 0.f;
  if (t < 150){
    int sA = dir ? (SS - 1) : 0;
    int sB = dir ? (SS - 2) : 1;
    cur0 = vx[(size_t)tok_sh[sA] * G4 + t];
    cur1 = vx[(size_t)tok_sh[sA] * G4 + t + 150];
    nx0  = vx[(size_t)tok_sh[sB] * G4 + t];
    nx1  = vx[(size_t)tok_sh[sB] * G4 + t + 150];
  } else if (t < 156 && dir == 0){
    cur0 = b_out[t - 150];  // bias folded into feature dot init
  }

  for (int k = 0; k <= SS; ++k){
    // ---- phase A: gate dots (step k) + feature dots (step k-1) ----
    float p0 = 0.f, p1 = 0.f;
    if (t < 150 && k + 2 < SS){
      int s2 = dir ? (SS - 3 - k) : (k + 2);
      int tok2 = tok_sh[s2];
      p0 = vx[(size_t)tok2 * G4 + t];          // depth-2 prefetch, survives the
      p1 = vx[(size_t)tok2 * G4 + t + 150];    // raw barriers (no vmcnt drain)
    }
    const float4 hv = *((const float4*)h_sh + lane);
    float a0 = cur0, a1 = 0.f, a2 = 0.f, a3 = 0.f;
    float d0 = cur1, d1 = 0.f, d2 = 0.f, d3 = 0.f;
    #pragma unroll
    for (int q = 0; q < 19; ++q){
      float e0 = RL(hv.x, q), e1 = RL(hv.y, q), e2 = RL(hv.z, q), e3 = RL(hv.w, q);
      a0 += e0 * GETW(wA0, wA1, wA2, wA3, wA4, 4 * q + 0);
      d0 += e0 * GETW(wB0, wB1, wB2, wB3, wB4, 4 * q + 0);
      a1 += e1 * GETW(wA0, wA1, wA2, wA3, wA4, 4 * q + 1);
      d1 += e1 * GETW(wB0, wB1, wB2, wB3, wB4, 4 * q + 1);
      a2 += e2 * GETW(wA0, wA1, wA2, wA3, wA4, 4 * q + 2);
      d2 += e2 * GETW(wB0, wB1, wB2, wB3, wB4, 4 * q + 2);
      a3 += e3 * GETW(wA0, wA1, wA2, wA3, wA4, 4 * q + 3);
      d3 += e3 * GETW(wB0, wB1, wB2, wB3, wB4, 4 * q + 3);
    }
    float r0 = (a0 + a1) + (a2 + a3);
    float r1 = (d0 + d1) + (d2 + d3);

    if (t < 150){
      if (k < SS){
        gates_sh[t] = r0;
        gates_sh[t + 150] = r1;
        cur0 = nx0; cur1 = nx1; nx0 = p0; nx1 = p1;
      }
    } else if (t < 156 && k > 0){
      int ps = dir ? (SS - k) : (k - 1);
      feats[((size_t)ps * BB + b) * TT + (t - 150)] = r0;
    }
    if (k == SS) break;
    sync_lds();
    // ---- phase B: activations (threads 0..74) ----
    if (t < HH){
      float gi = gates_sh[t];
      float gf = gates_sh[HH + t];
      float gg = gates_sh[2 * HH + t];
      float go = gates_sh[3 * HH + t];
      c = fast_sigmoid(gf) * c + fast_sigmoid(gi) * fast_tanh(gg);
      h_sh[t] = fast_sigmoid(go) * fast_tanh(c);
    }
    sync_lds();
  }
}

// ---------------- K3: CRF forward scan + gold score, 1 thread per batch ------
// Named scalars + amdgpu_waves_per_eu(1,1) so the ~130 live values (exp(T),
// gold-T, alpha, 4 prefetch stages) stay register-resident in the 512-step
// serial chain.
#define TAGW(g) tag4_sh[(g) * 64 + ((lane + (g)) & 63)]

#define LOADSTAGE(X0,X1,X2,Y0,Y1,Y2, srow) do{ \
  int _r = (srow); if (_r >= SS) _r = 0; \
  const float2* _pF = (const float2*)(featsF + ((size_t)_r * BB + b) * TT); \
  const float2* _pB = (const float2*)(featsB + ((size_t)_r * BB + b) * TT); \
  X0 = _pF[0]; X1 = _pF[1]; X2 = _pF[2]; \
  Y0 = _pB[0]; Y1 = _pB[1]; Y2 = _pB[2]; }while(0)

#define CSTEP(X0,X1,X2,Y0,Y1,Y2, tcn, srow) do{ \
  float F0 = X0.x + Y0.x, F1 = X0.y + Y0.y, F2 = X1.x + Y1.x; \
  float F3 = X1.y + Y1.y, F4 = X2.x + Y2.x, F5 = X2.y + Y2.y; \
  /* gold: emit + trans[tcn][tp] via select trees */ \
  float em = (tcn)==0 ? F0 : (tcn)==1 ? F1 : (tcn)==2 ? F2 : F3; \
  float c0s = tp==0?g00:tp==1?g01:tp==2?g02:tp==3?g03:g04; \
  float c1s = tp==0?g10:tp==1?g11:tp==2?g12:tp==3?g13:g14; \
  float c2s = tp==0?g20:tp==1?g21:tp==2?g22:tp==3?g23:g24; \
  float c3s = tp==0?g30:tp==1?g31:tp==2?g32:tp==3?g33:g34; \
  gold += em + ((tcn)==0?c0s:(tcn)==1?c1s:(tcn)==2?c2s:c3s); \
  tp = (tcn); \
  /* alpha update: a_j = M + log(sum_i exp(a_i-M)*exp(tr_ji)) + F_j */ \
  float M = fmaxf(fmaxf(fmaxf(a0,a1),fmaxf(a2,a3)),fmaxf(a4,a5)); \
  float e0 = __expf(a0-M), e1 = __expf(a1-M), e2 = __expf(a2-M); \
  float e3 = __expf(a3-M), e4 = __expf(a4-M), e5 = __expf(a5-M); \
  float s0 = e0*T00+e1*T01+e2*T02+e3*T03+e4*T04+e5*T05; \
  float s1 = e0*T10+e1*T11+e2*T12+e3*T13+e4*T14+e5*T15; \
  float s2 = e0*T20+e1*T21+e2*T22+e3*T23+e4*T24+e5*T25; \
  float s3 = e0*T30+e1*T31+e2*T32+e3*T33+e4*T34+e5*T35; \
  float s4 = e0*T40+e1*T41+e2*T42+e3*T43+e4*T44+e5*T45; \
  float s5 = e0*T50+e1*T51+e2*T52+e3*T53+e4*T54+e5*T55; \
  a0 = M + __logf(s0) + F0;  a1 = M + __logf(s1) + F1; \
  a2 = M + __logf(s2) + F2;  a3 = M + __logf(s3) + F3; \
  a4 = M + __logf(s4) + F4;  a5 = M + __logf(s5) + F5; \
  LOADSTAGE(X0,X1,X2,Y0,Y1,Y2, (srow) + 4); }while(0)

__global__ __launch_bounds__(64)
__attribute__((amdgpu_waves_per_eu(1, 1)))
void k_crf(
    const float* __restrict__ featsF, const float* __restrict__ featsB,
    const float* __restrict__ trans, const int* __restrict__ tags,
    float* __restrict__ out){
  __shared__ unsigned int tag4_sh[128 * 64];  // [s/4][swizzled lane] packed tags
  const int lane = threadIdx.x;
  const int b = blockIdx.x * 64 + lane;

  // stage tags: coalesced int4 global reads -> swizzled packed LDS words
  const int* tgblk = tags + (size_t)blockIdx.x * 64 * SS;
  for (int r = lane; r < 64 * 128; r += 64){
    int bi = r >> 7;        // batch-within-block 0..63
    int jj = r & 127;       // 4-step group 0..127
    int4 tv = ((const int4*)tgblk)[bi * 128 + jj];
    tag4_sh[jj * 64 + ((bi + jj) & 63)] =
        (unsigned)(tv.x & 255) | ((unsigned)(tv.y & 255) << 8) |
        ((unsigned)(tv.z & 255) << 16) | ((unsigned)(tv.w & 255) << 24);
  }
  __syncthreads();

  // exp(trans) matrix + gold transition entries, all named scalars
  float T00=__expf(trans[0]),  T01=__expf(trans[1]),  T02=__expf(trans[2]),  T03=__expf(trans[3]),  T04=__expf(trans[4]),  T05=__expf(trans[5]);
  float T10=__expf(trans[6]),  T11=__expf(trans[7]),  T12=__expf(trans[8]),  T13=__expf(trans[9]),  T14=__expf(trans[10]), T15=__expf(trans[11]);
  float T20=__expf(trans[12]), T21=__expf(trans[13]), T22=__expf(trans[14]), T23=__expf(trans[15]), T24=__expf(trans[16]), T25=__expf(trans[17]);
  float T30=__expf(trans[18]), T31=__expf(trans[19]), T32=__expf(trans[20]), T33=__expf(trans[21]), T34=__expf(trans[22]), T35=__expf(trans[23]);
  float T40=__expf(trans[24]), T41=__expf(trans[25]), T42=__expf(trans[26]), T43=__expf(trans[27]), T44=__expf(trans[28]), T45=__expf(trans[29]);
  float T50=__expf(trans[30]), T51=__expf(trans[31]), T52=__expf(trans[32]), T53=__expf(trans[33]), T54=__expf(trans[34]), T55=__expf(trans[35]);
  float g00=trans[0],  g01=trans[1],  g02=trans[2],  g03=trans[3],  g04=trans[4];
  float g10=trans[6],  g11=trans[7],  g12=trans[8],  g13=trans[9],  g14=trans[10];
  float g20=trans[12], g21=trans[13], g22=trans[14], g23=trans[15], g24=trans[16];
  float g30=trans[18], g31=trans[19], g32=trans[20], g33=trans[21], g34=trans[22];
  float g50=trans[30], g51=trans[31], g52=trans[32], g53=trans[33];
  float t54=trans[34], t55=trans[35];

  float a0 = NEGV, a1 = NEGV, a2 = NEGV, a3 = NEGV, a4 = 0.f, a5 = NEGV;
  float gold = 0.f;
  int tp = STARTT;

  float2 xA0,xA1,xA2,yA0,yA1,yA2, xB0,xB1,xB2,yB0,yB1,yB2;
  float2 xC0,xC1,xC2,yC0,yC1,yC2, xD0,xD1,xD2,yD0,yD1,yD2;
  LOADSTAGE(xA0,xA1,xA2,yA0,yA1,yA2, 0);
  LOADSTAGE(xB0,xB1,xB2,yB0,yB1,yB2, 1);
  LOADSTAGE(xC0,xC1,xC2,yC0,yC1,yC2, 2);
  LOADSTAGE(xD0,xD1,xD2,yD0,yD1,yD2, 3);

  unsigned twc = TAGW(0), twn = TAGW(1);
  for (int g = 0; g < 128; ++g){
    unsigned twp = TAGW(g + 2 < 128 ? g + 2 : 0);
    int u0 = twc & 255, u1 = (twc >> 8) & 255, u2 = (twc >> 16) & 255, u3 = twc >> 24;
    int sb = g * 4;
    CSTEP(xA0,xA1,xA2,yA0,yA1,yA2, u0, sb + 0);
    CSTEP(xB0,xB1,xB2,yB0,yB1,yB2, u1, sb + 1);
    CSTEP(xC0,xC1,xC2,yC0,yC1,yC2, u2, sb + 2);
    CSTEP(xD0,xD1,xD2,yD0,yD1,yD2, u3, sb + 3);
    twc = twn; twn = twp;
  }
  gold += (tp==0) ? g50 : (tp==1) ? g51 : (tp==2) ? g52 : g53;  // STOP <- last

  float z0 = a0 + g50, z1 = a1 + g51, z2 = a2 + g52;
  float z3 = a3 + g53, z4 = a4 + t54, z5 = a5 + t55;
  float M2 = fmaxf(fmaxf(fmaxf(z0,z1),fmaxf(z2,z3)),fmaxf(z4,z5));
  float ss = __expf(z0-M2)+__expf(z1-M2)+__expf(z2-M2)
           + __expf(z3-M2)+__expf(z4-M2)+__expf(z5-M2);
  out[b] = M2 + __logf(ss) - gold;
}

// ---------------- launch -----------------------------------------------------
extern "C" void kernel_launch(void* const* d_in, const int* in_sizes, int n_in,
                              void* d_out, int out_size, void* d_ws, size_t ws_size,
                              hipStream_t stream){
  const int*   sentence = (const int*)  d_in[0];
  const int*   tags     = (const int*)  d_in[1];
  const float* emb      = (const float*)d_in[2];
  const float* w_ih_f   = (const float*)d_in[3];
  const float* w_hh_f   = (const float*)d_in[4];
  const float* b_ih_f   = (const float*)d_in[5];
  const float* b_hh_f   = (const float*)d_in[6];
  const float* w_ih_b   = (const float*)d_in[7];
  const float* w_hh_b   = (const float*)d_in[8];
  const float* b_ih_b   = (const float*)d_in[9];
  const float* b_hh_b   = (const float*)d_in[10];
  const float* h0       = (const float*)d_in[11];
  const float* c0       = (const float*)d_in[12];
  const float* w_out    = (const float*)d_in[13];
  const float* b_out    = (const float*)d_in[14];
  const float* trans    = (const float*)d_in[15];
  float* out = (float*)d_out;

  float* ws = (float*)d_ws;
  float* vxg    = ws;                                 // [2][8000][300]
  float* featsF = vxg + (size_t)2 * VOCABN * G4;      // [512][256][6] (incl b_out)
  float* featsB = featsF + (size_t)SS * BB * TT;      // [512][256][6]

  k_gemm<<<2 * 63 * 5, 256, 0, stream>>>(emb, w_ih_f, w_ih_b,
                                         b_ih_f, b_hh_f, b_ih_b, b_hh_b, vxg);
  k_lstm<<<512, 192, 0, stream>>>(sentence, vxg, w_hh_f, w_hh_b, h0, c0, w_out, b_out,
                                  featsF, featsB);
  k_crf<<<BB / 64, 64, 0, stream>>>(featsF, featsB, trans, tags, out);
}

// Round 7
// 931.923 us; speedup vs baseline: 1.7075x; 1.1898x over previous
//
#include <hip/hip_runtime.h>
#include <stdint.h>

#define VOCABN 8000
#define EE     300
#define HH     75
#define G4     300   // 4*H
#define TT     6
#define BB     256
#define SS     512
#define STARTT 4
#define STOPT  5
#define NEGV   (-10000.0f)

typedef __fp16 fp16x2 __attribute__((ext_vector_type(2)));
typedef unsigned int u32;

__device__ __forceinline__ float fast_sigmoid(float x){
  return __builtin_amdgcn_rcpf(1.0f + __expf(-x));
}
__device__ __forceinline__ float fast_tanh(float x){
  x = fminf(15.0f, fmaxf(-15.0f, x));
  float e = __expf(2.0f * x);
  return (e - 1.0f) * __builtin_amdgcn_rcpf(e + 1.0f);
}

// pack two f32 into one dword of f16 pairs (RTZ pack instruction)
__device__ __forceinline__ float pk2(float a, float b){
  fp16x2 r = __builtin_amdgcn_cvt_pkrtz(a, b);
  return __builtin_bit_cast(float, r);
}
// D = dot(a.f16x2, b.f16x2) + c with f32 accumulate
__device__ __forceinline__ float dot2pk(float a, float b, float c){
  asm("v_dot2_f32_f16 %0, %1, %2, %0" : "+v"(c) : "v"(a), "v"(b));
  return c;
}

// raw barrier: orders LDS (lgkmcnt) but does NOT drain vmcnt -> global
// prefetches stay in flight across steps.
__device__ __forceinline__ void sync_lds(){
  __builtin_amdgcn_sched_barrier(0);
  asm volatile("s_waitcnt lgkmcnt(0)" ::: "memory");
  __builtin_amdgcn_s_barrier();
  __builtin_amdgcn_sched_barrier(0);
}

#define RL(x, l) __int_as_float(__builtin_amdgcn_readlane(__float_as_int(x), (l)))

// ---------------- K1: vocab_xg[dir][v][g] = emb[v] . w_ih[g] + b_ih[g]+b_hh[g]
#define LDSR 20
__global__ __launch_bounds__(256) void k_gemm(
    const float* __restrict__ emb, const float* __restrict__ w_ih_f,
    const float* __restrict__ w_ih_b,
    const float* __restrict__ b_ih_f, const float* __restrict__ b_hh_f,
    const float* __restrict__ b_ih_b, const float* __restrict__ b_hh_b,
    float* __restrict__ vxg){
  __shared__ alignas(16) float a_sh[128 * LDSR];
  __shared__ alignas(16) float b_sh[64 * LDSR];
  __shared__ float bias_sh[64];
  const int bx = blockIdx.x;
  const int dir = bx / (63 * 5);
  const int rem = bx % (63 * 5);
  const int vt = rem / 5, gt = rem % 5;
  const int v0 = vt * 128, g0 = gt * 64;
  const int tid = threadIdx.x;
  const float* wdir = dir ? w_ih_b : w_ih_f;

  if (tid < 64){
    int g = g0 + tid;
    float bi = 0.f;
    if (g < G4) bi = dir ? (b_ih_b[g] + b_hh_b[g]) : (b_ih_f[g] + b_hh_f[g]);
    bias_sh[tid] = bi;
  }

  float acc[8][4];
  #pragma unroll
  for (int i = 0; i < 8; ++i)
    #pragma unroll
    for (int j = 0; j < 4; ++j) acc[i][j] = 0.f;

  const int tx = tid & 15, ty = tid >> 4;
  const int la_r = tid >> 1, la_h = (tid & 1) * 8;
  const int lb_r = tid >> 2, lb_h = (tid & 3) * 4;

  const int va = v0 + la_r;
  const float* arow = emb + (size_t)(va < VOCABN ? va : 0) * EE;
  const int gb = g0 + lb_r;
  const float* brow = wdir + (size_t)(gb < G4 ? gb : 0) * EE;
  const float4 z4 = {0.f, 0.f, 0.f, 0.f};

  for (int kk = 0; kk < 19; ++kk){
    const int e0 = kk * 16;
    float4 av0 = *(const float4*)&arow[e0 + la_h];
    float4 av1 = (e0 + la_h + 7 < EE) ? *(const float4*)&arow[e0 + la_h + 4] : z4;
    float4 bv  = (e0 + lb_h + 3 < EE) ? *(const float4*)&brow[e0 + lb_h]     : z4;
    __syncthreads();
    *(float4*)&a_sh[la_r * LDSR + la_h]     = av0;
    *(float4*)&a_sh[la_r * LDSR + la_h + 4] = av1;
    *(float4*)&b_sh[lb_r * LDSR + lb_h]     = bv;
    __syncthreads();
    #pragma unroll
    for (int e4 = 0; e4 < 4; ++e4){
      float4 bq[4], aq[8];
      #pragma unroll
      for (int j = 0; j < 4; ++j) bq[j] = *(const float4*)&b_sh[(tx + 16 * j) * LDSR + e4 * 4];
      #pragma unroll
      for (int i = 0; i < 8; ++i) aq[i] = *(const float4*)&a_sh[(ty + 16 * i) * LDSR + e4 * 4];
      #pragma unroll
      for (int i = 0; i < 8; ++i)
        #pragma unroll
        for (int j = 0; j < 4; ++j)
          acc[i][j] += aq[i].x * bq[j].x + aq[i].y * bq[j].y
                     + aq[i].z * bq[j].z + aq[i].w * bq[j].w;
    }
  }

  const size_t obase = (size_t)dir * VOCABN * G4;
  #pragma unroll
  for (int i = 0; i < 8; ++i){
    int v = v0 + ty + 16 * i;
    if (v < VOCABN){
      #pragma unroll
      for (int j = 0; j < 4; ++j){
        int g = g0 + tx + 16 * j;
        if (g < G4) vxg[obase + (size_t)v * G4 + g] = acc[i][j] + bias_sh[tx + 16 * j];
      }
    }
  }
}

// ---------------- K2: per-(dir,batch) LSTM recurrence, feats fused -----------
// 1 gate-row per thread, weights packed f16-pairs: 38 dwords/thread (+~25
// overhead = ~65 live values, safely under the ~88 budget the RA grants -> no
// spill). h kept as packed f16 in LDS (160 B), broadcast via 1 ds_read_b128 +
// readlane, consumed by v_dot2_f32_f16 (f32 accumulate).
__global__ __launch_bounds__(320) void k_lstm(
    const int* __restrict__ sentence, const float* __restrict__ vxg,
    const float* __restrict__ w_hh_f, const float* __restrict__ w_hh_b,
    const float* __restrict__ h0, const float* __restrict__ c0,
    const float* __restrict__ w_out, const float* __restrict__ b_out,
    float* __restrict__ featsF, float* __restrict__ featsB){
  __shared__ alignas(16) u32 hpk[40];     // h as 40 dwords of f16 pairs (2 pad)
  __shared__ float gates_sh[G4];
  __shared__ int tok_sh[SS];
  const int dir = blockIdx.x >> 8;
  const int b = blockIdx.x & 255;
  const int t = threadIdx.x;
  const int lane = t & 63;

  for (int i = t; i < SS; i += 320) tok_sh[i] = sentence[b * SS + i];
  if (t >= 38 && t < 40) hpk[t] = 0;                        // pad dwords
  if (t == 75) ((__fp16*)hpk)[75] = (__fp16)0.f;            // pad half of dword 37

  // pack this thread's weight row f32 -> 38 f16-pair dwords
  float wp[38];
  #pragma unroll
  for (int p = 0; p < 38; ++p) wp[p] = 0.f;
  if (t < 300){
    const float* r0 = (dir ? w_hh_b : w_hh_f) + t * HH;
    #pragma unroll
    for (int p = 0; p < 37; ++p) wp[p] = pk2(r0[2 * p], r0[2 * p + 1]);
    wp[37] = pk2(r0[74], 0.f);
  } else if (t < 306){
    const float* r0 = w_out + (t - 300) * (2 * HH) + dir * HH;
    #pragma unroll
    for (int p = 0; p < 37; ++p) wp[p] = pk2(r0[2 * p], r0[2 * p + 1]);
    wp[37] = pk2(r0[74], 0.f);
  }

  float c = 0.f;
  if (t < HH){
    c = c0[((size_t)dir * BB + b) * HH + t];
    ((__fp16*)hpk)[t] = (__fp16)h0[((size_t)dir * BB + b) * HH + t];
  }
  __syncthreads();

  const float* vx = vxg + (size_t)dir * VOCABN * G4;
  float* feats = dir ? featsB : featsF;

  float cur = 0.f, nx = 0.f;
  if (t < 300){
    int sA = dir ? (SS - 1) : 0;
    int sB = dir ? (SS - 2) : 1;
    cur = vx[(size_t)tok_sh[sA] * G4 + t];
    nx  = vx[(size_t)tok_sh[sB] * G4 + t];
  } else if (t < 306 && dir == 0){
    cur = b_out[t - 300];  // bias folded into feature dot init (dir0 only)
  }

  for (int k = 0; k <= SS; ++k){
    // ---- phase A: gate dots (step k) + feature dots (step k-1) ----
    float p = 0.f;
    if (t < 300 && k + 2 < SS){
      int s2 = dir ? (SS - 3 - k) : (k + 2);
      p = vx[(size_t)tok_sh[s2] * G4 + t];   // depth-2 prefetch, survives barriers
    }
    const float4 hv = *((const float4*)hpk + (lane < 10 ? lane : 0));
    float a0 = cur, a1 = 0.f, a2 = 0.f, a3 = 0.f;
    #pragma unroll
    for (int q = 0; q < 10; ++q){
      float e0 = RL(hv.x, q);
      a0 = dot2pk(e0, wp[4 * q + 0], a0);
      if (4 * q + 1 < 38){ float e1 = RL(hv.y, q); a1 = dot2pk(e1, wp[4 * q + 1], a1); }
      if (4 * q + 2 < 38){ float e2 = RL(hv.z, q); a2 = dot2pk(e2, wp[4 * q + 2], a2); }
      if (4 * q + 3 < 38){ float e3 = RL(hv.w, q); a3 = dot2pk(e3, wp[4 * q + 3], a3); }
    }
    float r0 = (a0 + a1) + (a2 + a3);

    if (t < 300){
      if (k < SS){
        gates_sh[t] = r0;
        cur = nx; nx = p;
      }
    } else if (t < 306 && k > 0){
      int ps = dir ? (SS - k) : (k - 1);
      feats[((size_t)ps * BB + b) * TT + (t - 300)] = r0;
    }
    if (k == SS) break;
    sync_lds();
    // ---- phase B: activations (threads 0..74), h re-packed to f16 ----
    if (t < HH){
      float gi = gates_sh[t];
      float gf = gates_sh[HH + t];
      float gg = gates_sh[2 * HH + t];
      float go = gates_sh[3 * HH + t];
      c = fast_sigmoid(gf) * c + fast_sigmoid(gi) * fast_tanh(gg);
      float hval = fast_sigmoid(go) * fast_tanh(c);
      ((__fp16*)hpk)[t] = (__fp16)hval;
    }
    sync_lds();
  }
}

// ---------------- K3: CRF forward scan + gold score, 1 thread per batch ------
// Slim live-set version: exp(trans) packed f16 (18 dwords) consumed by dot2;
// gold transitions read from LDS (no 20-reg select trees); prefetch depth 2.
#define TAGW(g) tag4_sh[(g) * 64 + ((lane + (g)) & 63)]

#define LOADSTAGE(X0,X1,X2,Y0,Y1,Y2, srow) do{ \
  int _r = (srow); if (_r >= SS) _r = 0; \
  const float2* _pF = (const float2*)(featsF + ((size_t)_r * BB + b) * TT); \
  const float2* _pB = (const float2*)(featsB + ((size_t)_r * BB + b) * TT); \
  X0 = _pF[0]; X1 = _pF[1]; X2 = _pF[2]; \
  Y0 = _pB[0]; Y1 = _pB[1]; Y2 = _pB[2]; }while(0)

#define CSTEP(X0,X1,X2,Y0,Y1,Y2, tcn, srow) do{ \
  float F0 = X0.x + Y0.x, F1 = X0.y + Y0.y, F2 = X1.x + Y1.x; \
  float F3 = X1.y + Y1.y, F4 = X2.x + Y2.x, F5 = X2.y + Y2.y; \
  float em = (tcn)==0 ? F0 : (tcn)==1 ? F1 : (tcn)==2 ? F2 : F3; \
  gold += em + tr_sh[(tcn) * 6 + tp]; \
  tp = (tcn); \
  float M = fmaxf(fmaxf(fmaxf(a0,a1),fmaxf(a2,a3)),fmaxf(a4,a5)); \
  float p01 = pk2(__expf(a0-M), __expf(a1-M)); \
  float p23 = pk2(__expf(a2-M), __expf(a3-M)); \
  float p45 = pk2(__expf(a4-M), __expf(a5-M)); \
  float s0 = dot2pk(p45, Tp[2],  dot2pk(p23, Tp[1],  dot2pk(p01, Tp[0],  0.f))); \
  float s1 = dot2pk(p45, Tp[5],  dot2pk(p23, Tp[4],  dot2pk(p01, Tp[3],  0.f))); \
  float s2 = dot2pk(p45, Tp[8],  dot2pk(p23, Tp[7],  dot2pk(p01, Tp[6],  0.f))); \
  float s3 = dot2pk(p45, Tp[11], dot2pk(p23, Tp[10], dot2pk(p01, Tp[9],  0.f))); \
  float s4 = dot2pk(p45, Tp[14], dot2pk(p23, Tp[13], dot2pk(p01, Tp[12], 0.f))); \
  float s5 = dot2pk(p45, Tp[17], dot2pk(p23, Tp[16], dot2pk(p01, Tp[15], 0.f))); \
  a0 = M + __logf(s0) + F0;  a1 = M + __logf(s1) + F1; \
  a2 = M + __logf(s2) + F2;  a3 = M + __logf(s3) + F3; \
  a4 = M + __logf(s4) + F4;  a5 = M + __logf(s5) + F5; \
  LOADSTAGE(X0,X1,X2,Y0,Y1,Y2, (srow) + 2); }while(0)

__global__ __launch_bounds__(64) void k_crf(
    const float* __restrict__ featsF, const float* __restrict__ featsB,
    const float* __restrict__ trans, const int* __restrict__ tags,
    float* __restrict__ out){
  __shared__ float tr_sh[36];
  __shared__ u32 tag4_sh[128 * 64];  // [s/4][swizzled lane] packed tags
  const int lane = threadIdx.x;
  const int b = blockIdx.x * 64 + lane;

  if (lane < 36) tr_sh[lane] = trans[lane];

  // stage tags: coalesced int4 global reads -> swizzled packed LDS words
  const int* tgblk = tags + (size_t)blockIdx.x * 64 * SS;
  for (int r = lane; r < 64 * 128; r += 64){
    int bi = r >> 7;        // batch-within-block 0..63
    int jj = r & 127;       // 4-step group 0..127
    int4 tv = ((const int4*)tgblk)[bi * 128 + jj];
    tag4_sh[jj * 64 + ((bi + jj) & 63)] =
        (u32)(tv.x & 255) | ((u32)(tv.y & 255) << 8) |
        ((u32)(tv.z & 255) << 16) | ((u32)(tv.w & 255) << 24);
  }
  __syncthreads();

  // exp(trans) rows packed to f16 pairs: Tp[j*3+c] = pk(e^tr[j][2c], e^tr[j][2c+1])
  float Tp[18];
  #pragma unroll
  for (int j = 0; j < 6; ++j)
    #pragma unroll
    for (int cp = 0; cp < 3; ++cp)
      Tp[j * 3 + cp] = pk2(__expf(trans[j * 6 + 2 * cp]),
                           __expf(trans[j * 6 + 2 * cp + 1]));

  float a0 = NEGV, a1 = NEGV, a2 = NEGV, a3 = NEGV, a4 = 0.f, a5 = NEGV;
  float gold = 0.f;
  int tp = STARTT;

  float2 xA0,xA1,xA2,yA0,yA1,yA2, xB0,xB1,xB2,yB0,yB1,yB2;
  LOADSTAGE(xA0,xA1,xA2,yA0,yA1,yA2, 0);
  LOADSTAGE(xB0,xB1,xB2,yB0,yB1,yB2, 1);

  u32 twc = TAGW(0), twn = TAGW(1);
  for (int g = 0; g < 128; ++g){
    u32 twp = TAGW(g + 2 < 128 ? g + 2 : 0);
    int u0 = twc & 255, u1 = (twc >> 8) & 255, u2 = (twc >> 16) & 255, u3 = twc >> 24;
    int sb = g * 4;
    CSTEP(xA0,xA1,xA2,yA0,yA1,yA2, u0, sb + 0);
    CSTEP(xB0,xB1,xB2,yB0,yB1,yB2, u1, sb + 1);
    CSTEP(xA0,xA1,xA2,yA0,yA1,yA2, u2, sb + 2);
    CSTEP(xB0,xB1,xB2,yB0,yB1,yB2, u3, sb + 3);
    twc = twn; twn = twp;
  }
  gold += tr_sh[STOPT * 6 + tp];

  float z0 = a0 + tr_sh[30], z1 = a1 + tr_sh[31], z2 = a2 + tr_sh[32];
  float z3 = a3 + tr_sh[33], z4 = a4 + tr_sh[34], z5 = a5 + tr_sh[35];
  float M2 = fmaxf(fmaxf(fmaxf(z0,z1),fmaxf(z2,z3)),fmaxf(z4,z5));
  float ss = __expf(z0-M2)+__expf(z1-M2)+__expf(z2-M2)
           + __expf(z3-M2)+__expf(z4-M2)+__expf(z5-M2);
  out[b] = M2 + __logf(ss) - gold;
}

// ---------------- launch -----------------------------------------------------
extern "C" void kernel_launch(void* const* d_in, const int* in_sizes, int n_in,
                              void* d_out, int out_size, void* d_ws, size_t ws_size,
                              hipStream_t stream){
  const int*   sentence = (const int*)  d_in[0];
  const int*   tags     = (const int*)  d_in[1];
  const float* emb      = (const float*)d_in[2];
  const float* w_ih_f   = (const float*)d_in[3];
  const float* w_hh_f   = (const float*)d_in[4];
  const float* b_ih_f   = (const float*)d_in[5];
  const float* b_hh_f   = (const float*)d_in[6];
  const float* w_ih_b   = (const float*)d_in[7];
  const float* w_hh_b   = (const float*)d_in[8];
  const float* b_ih_b   = (const float*)d_in[9];
  const float* b_hh_b   = (const float*)d_in[10];
  const float* h0       = (const float*)d_in[11];
  const float* c0       = (const float*)d_in[12];
  const float* w_out    = (const float*)d_in[13];
  const float* b_out    = (const float*)d_in[14];
  const float* trans    = (const float*)d_in[15];
  float* out = (float*)d_out;

  float* ws = (float*)d_ws;
  float* vxg    = ws;                                 // [2][8000][300]
  float* featsF = vxg + (size_t)2 * VOCABN * G4;      // [512][256][6] (incl b_out)
  float* featsB = featsF + (size_t)SS * BB * TT;      // [512][256][6]

  k_gemm<<<2 * 63 * 5, 256, 0, stream>>>(emb, w_ih_f, w_ih_b,
                                         b_ih_f, b_hh_f, b_ih_b, b_hh_b, vxg);
  k_lstm<<<512, 320, 0, stream>>>(sentence, vxg, w_hh_f, w_hh_b, h0, c0, w_out, b_out,
                                  featsF, featsB);
  k_crf<<<BB / 64, 64, 0, stream>>>(featsF, featsB, trans, tags, out);
}

// Round 9
// 846.600 us; speedup vs baseline: 1.8795x; 1.1008x over previous
//
#include <hip/hip_runtime.h>
#include <stdint.h>

#define VOCABN 8000
#define EE     300
#define HH     75
#define G4     300   // 4*H
#define TT     6
#define BB     256
#define SS     512
#define STARTT 4
#define STOPT  5
#define NEGV   (-10000.0f)
#define NCH    16    // CRF chunks
#define CHL    32    // steps per chunk

typedef __fp16 fp16x2 __attribute__((ext_vector_type(2)));
typedef unsigned int u32;

__device__ __forceinline__ float fast_sigmoid(float x){
  return __builtin_amdgcn_rcpf(1.0f + __expf(-x));
}
__device__ __forceinline__ float fast_tanh(float x){
  x = fminf(15.0f, fmaxf(-15.0f, x));
  float e = __expf(2.0f * x);
  return (e - 1.0f) * __builtin_amdgcn_rcpf(e + 1.0f);
}
__device__ __forceinline__ float pk2(float a, float b){
  fp16x2 r = __builtin_amdgcn_cvt_pkrtz(a, b);
  return __builtin_bit_cast(float, r);
}
__device__ __forceinline__ float dot2pk(float a, float b, float c){
  asm("v_dot2_f32_f16 %0, %1, %2, %0" : "+v"(c) : "v"(a), "v"(b));
  return c;
}
__device__ __forceinline__ void sync_lds(){
  __builtin_amdgcn_sched_barrier(0);
  asm volatile("s_waitcnt lgkmcnt(0)" ::: "memory");
  __builtin_amdgcn_s_barrier();
  __builtin_amdgcn_sched_barrier(0);
}
#define RL(x, l) __int_as_float(__builtin_amdgcn_readlane(__float_as_int(x), (l)))

// ---------------- K1: vocab_xg[dir][v][g] = emb[v] . w_ih[g] + b_ih[g]+b_hh[g]
#define LDSR 20
__global__ __launch_bounds__(256) void k_gemm(
    const float* __restrict__ emb, const float* __restrict__ w_ih_f,
    const float* __restrict__ w_ih_b,
    const float* __restrict__ b_ih_f, const float* __restrict__ b_hh_f,
    const float* __restrict__ b_ih_b, const float* __restrict__ b_hh_b,
    float* __restrict__ vxg){
  __shared__ alignas(16) float a_sh[128 * LDSR];
  __shared__ alignas(16) float b_sh[64 * LDSR];
  __shared__ float bias_sh[64];
  const int bx = blockIdx.x;
  const int dir = bx / (63 * 5);
  const int rem = bx % (63 * 5);
  const int vt = rem / 5, gt = rem % 5;
  const int v0 = vt * 128, g0 = gt * 64;
  const int tid = threadIdx.x;
  const float* wdir = dir ? w_ih_b : w_ih_f;

  if (tid < 64){
    int g = g0 + tid;
    float bi = 0.f;
    if (g < G4) bi = dir ? (b_ih_b[g] + b_hh_b[g]) : (b_ih_f[g] + b_hh_f[g]);
    bias_sh[tid] = bi;
  }

  float acc[8][4];
  #pragma unroll
  for (int i = 0; i < 8; ++i)
    #pragma unroll
    for (int j = 0; j < 4; ++j) acc[i][j] = 0.f;

  const int tx = tid & 15, ty = tid >> 4;
  const int la_r = tid >> 1, la_h = (tid & 1) * 8;
  const int lb_r = tid >> 2, lb_h = (tid & 3) * 4;

  const int va = v0 + la_r;
  const float* arow = emb + (size_t)(va < VOCABN ? va : 0) * EE;
  const int gb = g0 + lb_r;
  const float* brow = wdir + (size_t)(gb < G4 ? gb : 0) * EE;
  const float4 z4 = {0.f, 0.f, 0.f, 0.f};

  for (int kk = 0; kk < 19; ++kk){
    const int e0 = kk * 16;
    float4 av0 = *(const float4*)&arow[e0 + la_h];
    float4 av1 = (e0 + la_h + 7 < EE) ? *(const float4*)&arow[e0 + la_h + 4] : z4;
    float4 bv  = (e0 + lb_h + 3 < EE) ? *(const float4*)&brow[e0 + lb_h]     : z4;
    __syncthreads();
    *(float4*)&a_sh[la_r * LDSR + la_h]     = av0;
    *(float4*)&a_sh[la_r * LDSR + la_h + 4] = av1;
    *(float4*)&b_sh[lb_r * LDSR + lb_h]     = bv;
    __syncthreads();
    #pragma unroll
    for (int e4 = 0; e4 < 4; ++e4){
      float4 bq[4], aq[8];
      #pragma unroll
      for (int j = 0; j < 4; ++j) bq[j] = *(const float4*)&b_sh[(tx + 16 * j) * LDSR + e4 * 4];
      #pragma unroll
      for (int i = 0; i < 8; ++i) aq[i] = *(const float4*)&a_sh[(ty + 16 * i) * LDSR + e4 * 4];
      #pragma unroll
      for (int i = 0; i < 8; ++i)
        #pragma unroll
        for (int j = 0; j < 4; ++j)
          acc[i][j] += aq[i].x * bq[j].x + aq[i].y * bq[j].y
                     + aq[i].z * bq[j].z + aq[i].w * bq[j].w;
    }
  }

  const size_t obase = (size_t)dir * VOCABN * G4;
  #pragma unroll
  for (int i = 0; i < 8; ++i){
    int v = v0 + ty + 16 * i;
    if (v < VOCABN){
      #pragma unroll
      for (int j = 0; j < 4; ++j){
        int g = g0 + tx + 16 * j;
        if (g < G4) vxg[obase + (size_t)v * G4 + g] = acc[i][j] + bias_sh[tx + 16 * j];
      }
    }
  }
}

// ---------------- K2: per-(dir,batch) LSTM recurrence, feats fused -----------
// Weights pinned in AGPRs (no MFMA in this kernel -> AGPR file is free, no
// allocation pressure -> cannot spill). v_accvgpr_read costs 1 VALU cycle vs
// ~200cy L2 scratch reload (rounds 2-7 disease: RA refuses >~20-elem VGPR
// arrays at this occupancy; 5 source-level attempts all spilled).
#define AG_ALL(F) F(0) F(1) F(2) F(3) F(4) F(5) F(6) F(7) F(8) F(9) \
  F(10) F(11) F(12) F(13) F(14) F(15) F(16) F(17) F(18) F(19) \
  F(20) F(21) F(22) F(23) F(24) F(25) F(26) F(27) F(28) F(29) \
  F(30) F(31) F(32) F(33) F(34) F(35) F(36) F(37)
#define AGDEF(i) float ag##i;
#define AGINIT(i) { float _v = pk2(wr[2*(i)], (2*(i)+1 < 75) ? wr[2*(i)+1] : 0.f); \
  asm volatile("v_accvgpr_write_b32 %0, %1" : "=a"(ag##i) : "v"(_v)); }
#define AGDOT(i, acc, h) { float _w; \
  asm("v_accvgpr_read_b32 %0, %1" : "=v"(_w) : "a"(ag##i)); \
  asm("v_dot2_f32_f16 %0, %1, %2, %0" : "+v"(acc) : "v"(h), "v"(_w)); }

__global__ __launch_bounds__(320) void k_lstm(
    const int* __restrict__ sentence, const float* __restrict__ vxg,
    const float* __restrict__ w_hh_f, const float* __restrict__ w_hh_b,
    const float* __restrict__ h0, const float* __restrict__ c0,
    const float* __restrict__ w_out, const float* __restrict__ b_out,
    float* __restrict__ featsF, float* __restrict__ featsB){
  __shared__ alignas(16) u32 hpk[40];     // h as 40 dwords of f16 pairs (2 pad)
  __shared__ float gates_sh[G4];
  __shared__ int tok_sh[SS];
  const int dir = blockIdx.x >> 8;
  const int b = blockIdx.x & 255;
  const int t = threadIdx.x;
  const int lane = t & 63;

  for (int i = t; i < SS; i += 320) tok_sh[i] = sentence[b * SS + i];
  if (t >= 38 && t < 40) hpk[t] = 0;                        // pad dwords
  if (t == 75) ((__fp16*)hpk)[75] = (__fp16)0.f;            // pad half of dword 37

  // weight row pointer (clamped for t>=306 so all lanes stay convergent)
  const float* wr = (t < 300) ? ((dir ? w_hh_b : w_hh_f) + t * HH)
                              : (w_out + ((t < 306) ? (t - 300) : 5) * (2 * HH) + dir * HH);
  AG_ALL(AGDEF)
  AG_ALL(AGINIT)

  float c = 0.f;
  if (t < HH){
    c = c0[((size_t)dir * BB + b) * HH + t];
    ((__fp16*)hpk)[t] = (__fp16)h0[((size_t)dir * BB + b) * HH + t];
  }
  __syncthreads();

  const float* vx = vxg + (size_t)dir * VOCABN * G4;
  float* feats = dir ? featsB : featsF;

  float cur = 0.f, nx = 0.f;
  if (t < 300){
    int sA = dir ? (SS - 1) : 0;
    int sB = dir ? (SS - 2) : 1;
    cur = vx[(size_t)tok_sh[sA] * G4 + t];
    nx  = vx[(size_t)tok_sh[sB] * G4 + t];
  } else if (t < 306 && dir == 0){
    cur = b_out[t - 300];  // bias folded into feature dot init (dir0 only)
  }

  for (int k = 0; k <= SS; ++k){
    // ---- phase A: gate dots (step k) + feature dots (step k-1) ----
    float p = 0.f;
    if (t < 300 && k + 2 < SS){
      int s2 = dir ? (SS - 3 - k) : (k + 2);
      p = vx[(size_t)tok_sh[s2] * G4 + t];   // depth-2 prefetch, survives barriers
    }
    const float4 hv = *((const float4*)hpk + (lane < 10 ? lane : 0));
    float a0 = cur, a1 = 0.f, a2 = 0.f, a3 = 0.f;
    float e;
    #define Q4(q, i0, i1, i2, i3) \
      e = RL(hv.x, q); AGDOT(i0, a0, e) \
      e = RL(hv.y, q); AGDOT(i1, a1, e) \
      e = RL(hv.z, q); AGDOT(i2, a2, e) \
      e = RL(hv.w, q); AGDOT(i3, a3, e)
    Q4(0, 0, 1, 2, 3)   Q4(1, 4, 5, 6, 7)   Q4(2, 8, 9, 10, 11)
    Q4(3, 12, 13, 14, 15) Q4(4, 16, 17, 18, 19) Q4(5, 20, 21, 22, 23)
    Q4(6, 24, 25, 26, 27) Q4(7, 28, 29, 30, 31) Q4(8, 32, 33, 34, 35)
    e = RL(hv.x, 9); AGDOT(36, a0, e)
    e = RL(hv.y, 9); AGDOT(37, a1, e)
    #undef Q4
    float r0 = (a0 + a1) + (a2 + a3);

    if (t < 300){
      if (k < SS){
        gates_sh[t] = r0;
        cur = nx; nx = p;
      }
    } else if (t < 306 && k > 0){
      int ps = dir ? (SS - k) : (k - 1);
      feats[((size_t)ps * BB + b) * TT + (t - 300)] = r0;
    }
    if (k == SS) break;
    sync_lds();
    // ---- phase B: activations (threads 0..74), h re-packed to f16 ----
    if (t < HH){
      float gi = gates_sh[t];
      float gf = gates_sh[HH + t];
      float gg = gates_sh[2 * HH + t];
      float go = gates_sh[3 * HH + t];
      c = fast_sigmoid(gf) * c + fast_sigmoid(gi) * fast_tanh(gg);
      float hval = fast_sigmoid(go) * fast_tanh(c);
      ((__fp16*)hpk)[t] = (__fp16)hval;
    }
    sync_lds();
  }
}

// ---------------- K3a: CRF chunked alpha-scan + gold partials ----------------
// Each CRF step is log-linear: a 32-step chunk's transfer matrix = 6
// independent alpha scans from basis inits. Round-8 fix: clamp the lse sum
// to 1e-37 before log — the STOP-basis row has ALL outgoing transitions
// blocked (exp(trans)=0 -> s_j=0 -> log(0)=-inf -> NaN next step). Clamped
// row sits ~-85 below valid rows: contribution exp(-85)~1e-37, as negligible
// as the true -10000 suppression, but finite.
#define LOADSTAGE(X0,X1,X2,Y0,Y1,Y2, srow) do{ \
  int _r = (srow); if (_r >= SS) _r = 0; \
  const float2* _pF = (const float2*)(featsF + ((size_t)_r * BB + b) * TT); \
  const float2* _pB = (const float2*)(featsB + ((size_t)_r * BB + b) * TT); \
  X0 = _pF[0]; X1 = _pF[1]; X2 = _pF[2]; \
  Y0 = _pB[0]; Y1 = _pB[1]; Y2 = _pB[2]; }while(0)

#define ASTEP(X0,X1,X2,Y0,Y1,Y2, srow) do{ \
  float F0 = X0.x + Y0.x, F1 = X0.y + Y0.y, F2 = X1.x + Y1.x; \
  float F3 = X1.y + Y1.y, F4 = X2.x + Y2.x, F5 = X2.y + Y2.y; \
  float M = fmaxf(fmaxf(fmaxf(a0,a1),fmaxf(a2,a3)),fmaxf(a4,a5)); \
  float p01 = pk2(__expf(a0-M), __expf(a1-M)); \
  float p23 = pk2(__expf(a2-M), __expf(a3-M)); \
  float p45 = pk2(__expf(a4-M), __expf(a5-M)); \
  float s0 = dot2pk(p45, Tq2,  dot2pk(p23, Tq1,  dot2pk(p01, Tq0,  0.f))); \
  float s1 = dot2pk(p45, Tq5,  dot2pk(p23, Tq4,  dot2pk(p01, Tq3,  0.f))); \
  float s2 = dot2pk(p45, Tq8,  dot2pk(p23, Tq7,  dot2pk(p01, Tq6,  0.f))); \
  float s3 = dot2pk(p45, Tq11, dot2pk(p23, Tq10, dot2pk(p01, Tq9,  0.f))); \
  float s4 = dot2pk(p45, Tq14, dot2pk(p23, Tq13, dot2pk(p01, Tq12, 0.f))); \
  float s5 = dot2pk(p45, Tq17, dot2pk(p23, Tq16, dot2pk(p01, Tq15, 0.f))); \
  a0 = M + __logf(fmaxf(s0, 1e-37f)) + F0;  a1 = M + __logf(fmaxf(s1, 1e-37f)) + F1; \
  a2 = M + __logf(fmaxf(s2, 1e-37f)) + F2;  a3 = M + __logf(fmaxf(s3, 1e-37f)) + F3; \
  a4 = M + __logf(fmaxf(s4, 1e-37f)) + F4;  a5 = M + __logf(fmaxf(s5, 1e-37f)) + F5; \
  LOADSTAGE(X0,X1,X2,Y0,Y1,Y2, (srow) + 2); }while(0)

__global__ __launch_bounds__(256) void k_crf_scan(
    const float* __restrict__ featsF, const float* __restrict__ featsB,
    const float* __restrict__ trans, const int* __restrict__ tags,
    float* __restrict__ crfM, float* __restrict__ pgold){
  __shared__ float tr_sh[36];
  __shared__ u32 etp_sh[18];
  const int tid = threadIdx.x;
  if (tid < 36) tr_sh[tid] = trans[tid];
  if (tid < 18) etp_sh[tid] = __float_as_uint(
      pk2(__expf(trans[2 * tid]), __expf(trans[2 * tid + 1])));
  __syncthreads();
  const int bx = blockIdx.x;

  if (bx < 96){
    // ---- alpha scan: thread = (b, chunk c, init state s0) ----
    const int g = bx * 256 + tid;
    const int s0i = g % 6;
    const int c = (g / 6) % NCH;
    const int b = g / (6 * NCH);
    const int cbase = c * CHL;

    float Tq0=__int_as_float(etp_sh[0]),  Tq1=__int_as_float(etp_sh[1]),
          Tq2=__int_as_float(etp_sh[2]),  Tq3=__int_as_float(etp_sh[3]),
          Tq4=__int_as_float(etp_sh[4]),  Tq5=__int_as_float(etp_sh[5]),
          Tq6=__int_as_float(etp_sh[6]),  Tq7=__int_as_float(etp_sh[7]),
          Tq8=__int_as_float(etp_sh[8]),  Tq9=__int_as_float(etp_sh[9]),
          Tq10=__int_as_float(etp_sh[10]), Tq11=__int_as_float(etp_sh[11]),
          Tq12=__int_as_float(etp_sh[12]), Tq13=__int_as_float(etp_sh[13]),
          Tq14=__int_as_float(etp_sh[14]), Tq15=__int_as_float(etp_sh[15]),
          Tq16=__int_as_float(etp_sh[16]), Tq17=__int_as_float(etp_sh[17]);

    float a0 = (s0i == 0) ? 0.f : NEGV, a1 = (s0i == 1) ? 0.f : NEGV;
    float a2 = (s0i == 2) ? 0.f : NEGV, a3 = (s0i == 3) ? 0.f : NEGV;
    float a4 = (s0i == 4) ? 0.f : NEGV, a5 = (s0i == 5) ? 0.f : NEGV;

    float2 xA0,xA1,xA2,yA0,yA1,yA2, xB0,xB1,xB2,yB0,yB1,yB2;
    LOADSTAGE(xA0,xA1,xA2,yA0,yA1,yA2, cbase + 0);
    LOADSTAGE(xB0,xB1,xB2,yB0,yB1,yB2, cbase + 1);
    for (int s = 0; s < CHL; s += 2){
      ASTEP(xA0,xA1,xA2,yA0,yA1,yA2, cbase + s);
      ASTEP(xB0,xB1,xB2,yB0,yB1,yB2, cbase + s + 1);
    }
    float* mrow = crfM + ((size_t)(b * NCH + c) * 6 + s0i) * 6;
    mrow[0] = a0; mrow[1] = a1; mrow[2] = a2;
    mrow[3] = a3; mrow[4] = a4; mrow[5] = a5;
  } else {
    // ---- gold partials: thread = (b, chunk c) ----
    const int g2 = (bx - 96) * 256 + tid;
    const int b = g2 / NCH;
    const int c = g2 % NCH;
    const int* tg = tags + (size_t)b * SS + c * CHL;
    int prev = (c == 0) ? STARTT : tg[-1];
    float acc = 0.f;
    #pragma unroll 4
    for (int s = 0; s < CHL; ++s){
      int ct = tg[s];
      size_t fo = (size_t)(c * CHL + s) * BB * TT + (size_t)b * TT + ct;
      acc += tr_sh[ct * 6 + prev] + featsF[fo] + featsB[fo];
      prev = ct;
    }
    pgold[b * NCH + c] = acc;
  }
}

// ---------------- K3b: combine 16 chunk matrices + finish -------------------
__global__ __launch_bounds__(64) void k_crf_comb(
    const float* __restrict__ crfM, const float* __restrict__ pgold,
    const float* __restrict__ trans, const int* __restrict__ tags,
    float* __restrict__ out){
  const int b = blockIdx.x * 64 + threadIdx.x;
  float v0 = NEGV, v1 = NEGV, v2 = NEGV, v3 = NEGV, v4 = 0.f, v5 = NEGV;
  for (int c = 0; c < NCH; ++c){
    const float* mb = crfM + (size_t)(b * NCH + c) * 36;
    float n[6];
    #pragma unroll
    for (int j = 0; j < 6; ++j){
      float t0 = v0 + mb[0 * 6 + j], t1 = v1 + mb[1 * 6 + j];
      float t2 = v2 + mb[2 * 6 + j], t3 = v3 + mb[3 * 6 + j];
      float t4 = v4 + mb[4 * 6 + j], t5 = v5 + mb[5 * 6 + j];
      float m = fmaxf(fmaxf(fmaxf(t0,t1),fmaxf(t2,t3)),fmaxf(t4,t5));
      float s = __expf(t0-m)+__expf(t1-m)+__expf(t2-m)
              + __expf(t3-m)+__expf(t4-m)+__expf(t5-m);
      n[j] = m + __logf(s);
    }
    v0 = n[0]; v1 = n[1]; v2 = n[2]; v3 = n[3]; v4 = n[4]; v5 = n[5];
  }
  float z0 = v0 + trans[30], z1 = v1 + trans[31], z2 = v2 + trans[32];
  float z3 = v3 + trans[33], z4 = v4 + trans[34], z5 = v5 + trans[35];
  float M2 = fmaxf(fmaxf(fmaxf(z0,z1),fmaxf(z2,z3)),fmaxf(z4,z5));
  float ss = __expf(z0-M2)+__expf(z1-M2)+__expf(z2-M2)
           + __expf(z3-M2)+__expf(z4-M2)+__expf(z5-M2);
  float fwd = M2 + __logf(ss);

  float gold = trans[STOPT * 6 + tags[(size_t)b * SS + SS - 1]];
  #pragma unroll
  for (int c = 0; c < NCH; ++c) gold += pgold[b * NCH + c];
  out[b] = fwd - gold;
}

// ---------------- launch -----------------------------------------------------
extern "C" void kernel_launch(void* const* d_in, const int* in_sizes, int n_in,
                              void* d_out, int out_size, void* d_ws, size_t ws_size,
                              hipStream_t stream){
  const int*   sentence = (const int*)  d_in[0];
  const int*   tags     = (const int*)  d_in[1];
  const float* emb      = (const float*)d_in[2];
  const float* w_ih_f   = (const float*)d_in[3];
  const float* w_hh_f   = (const float*)d_in[4];
  const float* b_ih_f   = (const float*)d_in[5];
  const float* b_hh_f   = (const float*)d_in[6];
  const float* w_ih_b   = (const float*)d_in[7];
  const float* w_hh_b   = (const float*)d_in[8];
  const float* b_ih_b   = (const float*)d_in[9];
  const float* b_hh_b   = (const float*)d_in[10];
  const float* h0       = (const float*)d_in[11];
  const float* c0       = (const float*)d_in[12];
  const float* w_out    = (const float*)d_in[13];
  const float* b_out    = (const float*)d_in[14];
  const float* trans    = (const float*)d_in[15];
  float* out = (float*)d_out;

  float* ws = (float*)d_ws;
  float* vxg    = ws;                                 // [2][8000][300]
  float* featsF = vxg + (size_t)2 * VOCABN * G4;      // [512][256][6] (incl b_out)
  float* featsB = featsF + (size_t)SS * BB * TT;      // [512][256][6]
  float* crfM   = featsB + (size_t)SS * BB * TT;      // [256][16][6][6]
  float* pgold  = crfM + (size_t)BB * NCH * 36;       // [256][16]

  k_gemm<<<2 * 63 * 5, 256, 0, stream>>>(emb, w_ih_f, w_ih_b,
                                         b_ih_f, b_hh_f, b_ih_b, b_hh_b, vxg);
  k_lstm<<<512, 320, 0, stream>>>(sentence, vxg, w_hh_f, w_hh_b, h0, c0, w_out, b_out,
                                  featsF, featsB);
  k_crf_scan<<<96 + 16, 256, 0, stream>>>(featsF, featsB, trans, tags, crfM, pgold);
  k_crf_comb<<<BB / 64, 64, 0, stream>>>(crfM, pgold, trans, tags, out);
}

// Round 10
// 551.125 us; speedup vs baseline: 2.8872x; 1.5361x over previous
//
#include <hip/hip_runtime.h>
#include <stdint.h>

#define VOCABN 8000
#define EE     300
#define HH     75
#define G4     300   // 4*H
#define TT     6
#define BB     256
#define SS     512
#define STARTT 4
#define STOPT  5
#define NEGV   (-10000.0f)
#define NCH    16    // CRF chunks
#define CHL    32    // steps per chunk
#define HROW   104   // padded f16 row stride for h LDS (bank-friendly, >=96)

typedef __fp16 fp16x2 __attribute__((ext_vector_type(2)));
typedef __fp16 f16x8 __attribute__((ext_vector_type(8)));
typedef float f32x4 __attribute__((ext_vector_type(4)));
typedef unsigned int u32;

__device__ __forceinline__ float sigf(float x){
  return __builtin_amdgcn_rcpf(1.0f + __expf(-x));   // saturates cleanly, no NaN
}
__device__ __forceinline__ float tanhf_(float x){
  return __builtin_fmaf(__builtin_amdgcn_rcpf(1.0f + __expf(-2.0f * x)), 2.0f, -1.0f);
}
__device__ __forceinline__ float pk2(float a, float b){
  fp16x2 r = __builtin_amdgcn_cvt_pkrtz(a, b);
  return __builtin_bit_cast(float, r);
}
__device__ __forceinline__ float dot2pk(float a, float b, float c){
  asm("v_dot2_f32_f16 %0, %1, %2, %0" : "+v"(c) : "v"(a), "v"(b));
  return c;
}
// raw barrier: orders LDS, leaves global prefetches in flight
__device__ __forceinline__ void sync_lds(){
  __builtin_amdgcn_sched_barrier(0);
  asm volatile("s_waitcnt lgkmcnt(0)" ::: "memory");
  __builtin_amdgcn_s_barrier();
  __builtin_amdgcn_sched_barrier(0);
}

// ---------------- K1: vocab_xg[dir][v][g'] with PERMUTED gate order ----------
// g' = 4*(g%75) + g/75  => quad (i,f,g,o) of h-index lands contiguous, matching
// the MFMA D-fragment layout in k_lstm (row = 4q+reg).
#define LDSR 20
__global__ __launch_bounds__(256) void k_gemm(
    const float* __restrict__ emb, const float* __restrict__ w_ih_f,
    const float* __restrict__ w_ih_b,
    const float* __restrict__ b_ih_f, const float* __restrict__ b_hh_f,
    const float* __restrict__ b_ih_b, const float* __restrict__ b_hh_b,
    float* __restrict__ vxg){
  __shared__ alignas(16) float a_sh[128 * LDSR];
  __shared__ alignas(16) float b_sh[64 * LDSR];
  __shared__ float bias_sh[64];
  const int bx = blockIdx.x;
  const int dir = bx / (63 * 5);
  const int rem = bx % (63 * 5);
  const int vt = rem / 5, gt = rem % 5;
  const int v0 = vt * 128, g0 = gt * 64;
  const int tid = threadIdx.x;
  const float* wdir = dir ? w_ih_b : w_ih_f;

  if (tid < 64){
    int g = g0 + tid;
    float bi = 0.f;
    if (g < G4) bi = dir ? (b_ih_b[g] + b_hh_b[g]) : (b_ih_f[g] + b_hh_f[g]);
    bias_sh[tid] = bi;
  }

  float acc[8][4];
  #pragma unroll
  for (int i = 0; i < 8; ++i)
    #pragma unroll
    for (int j = 0; j < 4; ++j) acc[i][j] = 0.f;

  const int tx = tid & 15, ty = tid >> 4;
  const int la_r = tid >> 1, la_h = (tid & 1) * 8;
  const int lb_r = tid >> 2, lb_h = (tid & 3) * 4;

  const int va = v0 + la_r;
  const float* arow = emb + (size_t)(va < VOCABN ? va : 0) * EE;
  const int gb = g0 + lb_r;
  const float* brow = wdir + (size_t)(gb < G4 ? gb : 0) * EE;
  const float4 z4 = {0.f, 0.f, 0.f, 0.f};

  for (int kk = 0; kk < 19; ++kk){
    const int e0 = kk * 16;
    float4 av0 = *(const float4*)&arow[e0 + la_h];
    float4 av1 = (e0 + la_h + 7 < EE) ? *(const float4*)&arow[e0 + la_h + 4] : z4;
    float4 bv  = (e0 + lb_h + 3 < EE) ? *(const float4*)&brow[e0 + lb_h]     : z4;
    __syncthreads();
    *(float4*)&a_sh[la_r * LDSR + la_h]     = av0;
    *(float4*)&a_sh[la_r * LDSR + la_h + 4] = av1;
    *(float4*)&b_sh[lb_r * LDSR + lb_h]     = bv;
    __syncthreads();
    #pragma unroll
    for (int e4 = 0; e4 < 4; ++e4){
      float4 bq[4], aq[8];
      #pragma unroll
      for (int j = 0; j < 4; ++j) bq[j] = *(const float4*)&b_sh[(tx + 16 * j) * LDSR + e4 * 4];
      #pragma unroll
      for (int i = 0; i < 8; ++i) aq[i] = *(const float4*)&a_sh[(ty + 16 * i) * LDSR + e4 * 4];
      #pragma unroll
      for (int i = 0; i < 8; ++i)
        #pragma unroll
        for (int j = 0; j < 4; ++j)
          acc[i][j] += aq[i].x * bq[j].x + aq[i].y * bq[j].y
                     + aq[i].z * bq[j].z + aq[i].w * bq[j].w;
    }
  }

  const size_t obase = (size_t)dir * VOCABN * G4;
  #pragma unroll
  for (int i = 0; i < 8; ++i){
    int v = v0 + ty + 16 * i;
    if (v < VOCABN){
      #pragma unroll
      for (int j = 0; j < 4; ++j){
        int g = g0 + tx + 16 * j;
        if (g < G4){
          int gp = 4 * (g % 75) + (g / 75);   // permuted gate index
          vxg[obase + (size_t)v * G4 + gp] = acc[i][j] + bias_sh[tx + 16 * j];
        }
      }
    }
  }
}

// ---------------- K2: MFMA BiLSTM, 16 batch per block ------------------------
// Per step: D[320][16] = W[320][96] . h[96][16] via 16x16x32 f16 MFMA.
// M-rows 0..299 = permuted gates (quad per lane), 300..305 = w_out feat rows.
// h double-buffered f16 in LDS -> ONE barrier per step. Weights in AGPRs
// ("a" MFMA operands) -> immune to the VGPR-spill disease of rounds 2-9.
__global__ __launch_bounds__(640) void k_lstm(
    const int* __restrict__ sentence, const float* __restrict__ vxg,
    const float* __restrict__ w_hh_f, const float* __restrict__ w_hh_b,
    const float* __restrict__ h0, const float* __restrict__ c0,
    const float* __restrict__ w_out, const float* __restrict__ b_out,
    float* __restrict__ featsF, float* __restrict__ featsB){
  __shared__ int tok_sh[SS * 16];
  __shared__ alignas(16) __fp16 hp[2][16 * HROW];
  const int bx = blockIdx.x;
  const int dir = bx >> 4, group = bx & 15;
  const int t = threadIdx.x;
  const int w = t >> 6, lane = t & 63;
  const int bb = lane & 15, q = lane >> 4;
  const int T0 = 2 * w, T1 = 2 * w + 1;
  const int rbA = 16 * T0 + 4 * q, rbB = 16 * T1 + 4 * q;
  const int hA = rbA >> 2, hB = rbB >> 2;
  const int bglob = group * 16 + bb;

  for (int i = t; i < 16 * HROW; i += 640) ((u32*)hp)[i] = 0;  // both buffers
  for (int i = t; i < 16 * SS; i += 640){
    int bq = i >> 9, s = i & 511;
    tok_sh[s * 16 + ((bq + s) & 15)] = sentence[(size_t)(group * 16 + bq) * SS + s];
  }
  __syncthreads();

  const float* whh = dir ? w_hh_b : w_hh_f;
  f16x8 a00, a01, a02, a10, a11, a12;
  #define BUILD_A(dst, T, c) { \
    int m = 16 * (T) + bb; int kb = 32 * (c) + 8 * q; \
    _Pragma("unroll") \
    for (int j = 0; j < 8; ++j){ \
      int kk = kb + j; float wv = 0.f; \
      if (kk < HH){ \
        if (m < 300) wv = whh[((m & 3) * 75 + (m >> 2)) * HH + kk]; \
        else if (m < 306) wv = w_out[(m - 300) * (2 * HH) + dir * HH + kk]; \
      } \
      dst[j] = (__fp16)wv; } }
  BUILD_A(a00, T0, 0) BUILD_A(a01, T0, 1) BUILD_A(a02, T0, 2)
  BUILD_A(a10, T1, 0) BUILD_A(a11, T1, 1) BUILD_A(a12, T1, 2)

  float cA = 0.f, cB = 0.f;
  if (hA < HH){
    cA = c0[((size_t)dir * BB + bglob) * HH + hA];
    hp[0][bb * HROW + hA] = (__fp16)h0[((size_t)dir * BB + bglob) * HH + hA];
  }
  if (hB < HH){
    cB = c0[((size_t)dir * BB + bglob) * HH + hB];
    hp[0][bb * HROW + hB] = (__fp16)h0[((size_t)dir * BB + bglob) * HH + hB];
  }
  const float bo0 = dir ? 0.f : b_out[0], bo1 = dir ? 0.f : b_out[1];
  const float bo2 = dir ? 0.f : b_out[2], bo3 = dir ? 0.f : b_out[3];
  const float bo4 = dir ? 0.f : b_out[4], bo5 = dir ? 0.f : b_out[5];
  __syncthreads();

  const float* vx = vxg + (size_t)dir * VOCABN * G4;
  float* feats = dir ? featsB : featsF;
  const float4 zf4 = {0.f, 0.f, 0.f, 0.f};

  float4 cur0 = zf4, cur1 = zf4, nx0 = zf4, nx1 = zf4;
  {
    int p = dir ? (SS - 1) : 0;
    int tk = tok_sh[p * 16 + ((bb + p) & 15)];
    const float* base = vx + (size_t)tk * G4;
    if (hA < HH) cur0 = *(const float4*)(base + rbA);
    if (hB < HH) cur1 = *(const float4*)(base + rbB);
    p = dir ? (SS - 2) : 1;
    tk = tok_sh[p * 16 + ((bb + p) & 15)];
    base = vx + (size_t)tk * G4;
    if (hA < HH) nx0 = *(const float4*)(base + rbA);
    if (hB < HH) nx1 = *(const float4*)(base + rbB);
  }

  for (int k = 0; k <= SS; ++k){
    const __fp16* hq = hp[k & 1];
    const int bofs = bb * HROW + 8 * q;
    f16x8 b0 = *(const f16x8*)&hq[bofs];
    f16x8 b1 = *(const f16x8*)&hq[bofs + 32];
    f16x8 b2 = *(const f16x8*)&hq[bofs + 64];

    float4 p0 = zf4, p1 = zf4;
    if (k + 2 < SS){                        // depth-2 xg prefetch
      int p = dir ? (SS - 3 - k) : (k + 2);
      int tk = tok_sh[p * 16 + ((bb + p) & 15)];
      const float* base = vx + (size_t)tk * G4;
      if (hA < HH) p0 = *(const float4*)(base + rbA);
      if (hB < HH) p1 = *(const float4*)(base + rbB);
    }

    f32x4 acc0 = {0.f, 0.f, 0.f, 0.f}, acc1 = {0.f, 0.f, 0.f, 0.f};
    asm("v_mfma_f32_16x16x32_f16 %0, %1, %2, %0" : "+v"(acc0) : "a"(a00), "v"(b0));
    asm("v_mfma_f32_16x16x32_f16 %0, %1, %2, %0" : "+v"(acc1) : "a"(a10), "v"(b0));
    asm("v_mfma_f32_16x16x32_f16 %0, %1, %2, %0" : "+v"(acc0) : "a"(a01), "v"(b1));
    asm("v_mfma_f32_16x16x32_f16 %0, %1, %2, %0" : "+v"(acc1) : "a"(a11), "v"(b1));
    asm("v_mfma_f32_16x16x32_f16 %0, %1, %2, %0" : "+v"(acc0) : "a"(a02), "v"(b2));
    asm("v_mfma_f32_16x16x32_f16 %0, %1, %2, %0" : "+v"(acc1) : "a"(a12), "v"(b2));

    __fp16* hw = hp[(k & 1) ^ 1];
    if (k < SS){
      if (hA < HH){
        float gi = acc0.x + cur0.x, gf = acc0.y + cur0.y;
        float gg = acc0.z + cur0.z, go = acc0.w + cur0.w;
        cA = sigf(gf) * cA + sigf(gi) * tanhf_(gg);
        hw[bb * HROW + hA] = (__fp16)(sigf(go) * tanhf_(cA));
      }
      if (hB < HH){
        float gi = acc1.x + cur1.x, gf = acc1.y + cur1.y;
        float gg = acc1.z + cur1.z, go = acc1.w + cur1.w;
        cB = sigf(gf) * cB + sigf(gi) * tanhf_(gg);
        hw[bb * HROW + hB] = (__fp16)(sigf(go) * tanhf_(cB));
      }
    }
    if (k >= 1){
      if (rbA == 300){                       // feat rows 0..3 (wave 9, q=3)
        int ps = dir ? (SS - k) : (k - 1);
        float* fb = feats + ((size_t)ps * BB + bglob) * TT;
        float2 v01 = {acc0.x + bo0, acc0.y + bo1};
        float2 v23 = {acc0.z + bo2, acc0.w + bo3};
        *(float2*)fb = v01;
        *(float2*)(fb + 2) = v23;
      }
      if (rbB == 304){                       // feat rows 4..5 (wave 9, q=0)
        int ps = dir ? (SS - k) : (k - 1);
        float* fb = feats + ((size_t)ps * BB + bglob) * TT;
        float2 v45 = {acc1.x + bo4, acc1.y + bo5};
        *(float2*)(fb + 4) = v45;
      }
    }
    cur0 = nx0; cur1 = nx1; nx0 = p0; nx1 = p1;
    sync_lds();
  }
}

// ---------------- K3a: CRF chunked alpha-scan + gold partials ----------------
#define LOADSTAGE(X0,X1,X2,Y0,Y1,Y2, srow) do{ \
  int _r = (srow); if (_r >= SS) _r = 0; \
  const float2* _pF = (const float2*)(featsF + ((size_t)_r * BB + b) * TT); \
  const float2* _pB = (const float2*)(featsB + ((size_t)_r * BB + b) * TT); \
  X0 = _pF[0]; X1 = _pF[1]; X2 = _pF[2]; \
  Y0 = _pB[0]; Y1 = _pB[1]; Y2 = _pB[2]; }while(0)

#define ASTEP(X0,X1,X2,Y0,Y1,Y2, srow) do{ \
  float F0 = X0.x + Y0.x, F1 = X0.y + Y0.y, F2 = X1.x + Y1.x; \
  float F3 = X1.y + Y1.y, F4 = X2.x + Y2.x, F5 = X2.y + Y2.y; \
  float M = fmaxf(fmaxf(fmaxf(a0,a1),fmaxf(a2,a3)),fmaxf(a4,a5)); \
  float p01 = pk2(__expf(a0-M), __expf(a1-M)); \
  float p23 = pk2(__expf(a2-M), __expf(a3-M)); \
  float p45 = pk2(__expf(a4-M), __expf(a5-M)); \
  float s0 = dot2pk(p45, Tq2,  dot2pk(p23, Tq1,  dot2pk(p01, Tq0,  0.f))); \
  float s1 = dot2pk(p45, Tq5,  dot2pk(p23, Tq4,  dot2pk(p01, Tq3,  0.f))); \
  float s2 = dot2pk(p45, Tq8,  dot2pk(p23, Tq7,  dot2pk(p01, Tq6,  0.f))); \
  float s3 = dot2pk(p45, Tq11, dot2pk(p23, Tq10, dot2pk(p01, Tq9,  0.f))); \
  float s4 = dot2pk(p45, Tq14, dot2pk(p23, Tq13, dot2pk(p01, Tq12, 0.f))); \
  float s5 = dot2pk(p45, Tq17, dot2pk(p23, Tq16, dot2pk(p01, Tq15, 0.f))); \
  a0 = M + __logf(fmaxf(s0, 1e-37f)) + F0;  a1 = M + __logf(fmaxf(s1, 1e-37f)) + F1; \
  a2 = M + __logf(fmaxf(s2, 1e-37f)) + F2;  a3 = M + __logf(fmaxf(s3, 1e-37f)) + F3; \
  a4 = M + __logf(fmaxf(s4, 1e-37f)) + F4;  a5 = M + __logf(fmaxf(s5, 1e-37f)) + F5; \
  LOADSTAGE(X0,X1,X2,Y0,Y1,Y2, (srow) + 2); }while(0)

__global__ __launch_bounds__(256) void k_crf_scan(
    const float* __restrict__ featsF, const float* __restrict__ featsB,
    const float* __restrict__ trans, const int* __restrict__ tags,
    float* __restrict__ crfM, float* __restrict__ pgold){
  __shared__ float tr_sh[36];
  __shared__ u32 etp_sh[18];
  const int tid = threadIdx.x;
  if (tid < 36) tr_sh[tid] = trans[tid];
  if (tid < 18) etp_sh[tid] = __float_as_uint(
      pk2(__expf(trans[2 * tid]), __expf(trans[2 * tid + 1])));
  __syncthreads();
  const int bx = blockIdx.x;

  if (bx < 96){
    const int g = bx * 256 + tid;
    const int s0i = g % 6;
    const int c = (g / 6) % NCH;
    const int b = g / (6 * NCH);
    const int cbase = c * CHL;

    float Tq0=__int_as_float(etp_sh[0]),  Tq1=__int_as_float(etp_sh[1]),
          Tq2=__int_as_float(etp_sh[2]),  Tq3=__int_as_float(etp_sh[3]),
          Tq4=__int_as_float(etp_sh[4]),  Tq5=__int_as_float(etp_sh[5]),
          Tq6=__int_as_float(etp_sh[6]),  Tq7=__int_as_float(etp_sh[7]),
          Tq8=__int_as_float(etp_sh[8]),  Tq9=__int_as_float(etp_sh[9]),
          Tq10=__int_as_float(etp_sh[10]), Tq11=__int_as_float(etp_sh[11]),
          Tq12=__int_as_float(etp_sh[12]), Tq13=__int_as_float(etp_sh[13]),
          Tq14=__int_as_float(etp_sh[14]), Tq15=__int_as_float(etp_sh[15]),
          Tq16=__int_as_float(etp_sh[16]), Tq17=__int_as_float(etp_sh[17]);

    float a0 = (s0i == 0) ? 0.f : NEGV, a1 = (s0i == 1) ? 0.f : NEGV;
    float a2 = (s0i == 2) ? 0.f : NEGV, a3 = (s0i == 3) ? 0.f : NEGV;
    float a4 = (s0i == 4) ? 0.f : NEGV, a5 = (s0i == 5) ? 0.f : NEGV;

    float2 xA0,xA1,xA2,yA0,yA1,yA2, xB0,xB1,xB2,yB0,yB1,yB2;
    LOADSTAGE(xA0,xA1,xA2,yA0,yA1,yA2, cbase + 0);
    LOADSTAGE(xB0,xB1,xB2,yB0,yB1,yB2, cbase + 1);
    for (int s = 0; s < CHL; s += 2){
      ASTEP(xA0,xA1,xA2,yA0,yA1,yA2, cbase + s);
      ASTEP(xB0,xB1,xB2,yB0,yB1,yB2, cbase + s + 1);
    }
    float* mrow = crfM + ((size_t)(b * NCH + c) * 6 + s0i) * 6;
    mrow[0] = a0; mrow[1] = a1; mrow[2] = a2;
    mrow[3] = a3; mrow[4] = a4; mrow[5] = a5;
  } else {
    const int g2 = (bx - 96) * 256 + tid;
    const int b = g2 / NCH;
    const int c = g2 % NCH;
    const int* tg = tags + (size_t)b * SS + c * CHL;
    int prev = (c == 0) ? STARTT : tg[-1];
    float acc = 0.f;
    #pragma unroll 4
    for (int s = 0; s < CHL; ++s){
      int ct = tg[s];
      size_t fo = (size_t)(c * CHL + s) * BB * TT + (size_t)b * TT + ct;
      acc += tr_sh[ct * 6 + prev] + featsF[fo] + featsB[fo];
      prev = ct;
    }
    pgold[b * NCH + c] = acc;
  }
}

// ---------------- K3b: combine 16 chunk matrices + finish -------------------
__global__ __launch_bounds__(64) void k_crf_comb(
    const float* __restrict__ crfM, const float* __restrict__ pgold,
    const float* __restrict__ trans, const int* __restrict__ tags,
    float* __restrict__ out){
  const int b = blockIdx.x * 64 + threadIdx.x;
  float v0 = NEGV, v1 = NEGV, v2 = NEGV, v3 = NEGV, v4 = 0.f, v5 = NEGV;
  for (int c = 0; c < NCH; ++c){
    const float* mb = crfM + (size_t)(b * NCH + c) * 36;
    float n[6];
    #pragma unroll
    for (int j = 0; j < 6; ++j){
      float t0 = v0 + mb[0 * 6 + j], t1 = v1 + mb[1 * 6 + j];
      float t2 = v2 + mb[2 * 6 + j], t3 = v3 + mb[3 * 6 + j];
      float t4 = v4 + mb[4 * 6 + j], t5 = v5 + mb[5 * 6 + j];
      float m = fmaxf(fmaxf(fmaxf(t0,t1),fmaxf(t2,t3)),fmaxf(t4,t5));
      float s = __expf(t0-m)+__expf(t1-m)+__expf(t2-m)
              + __expf(t3-m)+__expf(t4-m)+__expf(t5-m);
      n[j] = m + __logf(s);
    }
    v0 = n[0]; v1 = n[1]; v2 = n[2]; v3 = n[3]; v4 = n[4]; v5 = n[5];
  }
  float z0 = v0 + trans[30], z1 = v1 + trans[31], z2 = v2 + trans[32];
  float z3 = v3 + trans[33], z4 = v4 + trans[34], z5 = v5 + trans[35];
  float M2 = fmaxf(fmaxf(fmaxf(z0,z1),fmaxf(z2,z3)),fmaxf(z4,z5));
  float ss = __expf(z0-M2)+__expf(z1-M2)+__expf(z2-M2)
           + __expf(z3-M2)+__expf(z4-M2)+__expf(z5-M2);
  float fwd = M2 + __logf(ss);

  float gold = trans[STOPT * 6 + tags[(size_t)b * SS + SS - 1]];
  #pragma unroll
  for (int c = 0; c < NCH; ++c) gold += pgold[b * NCH + c];
  out[b] = fwd - gold;
}

// ---------------- launch -----------------------------------------------------
extern "C" void kernel_launch(void* const* d_in, const int* in_sizes, int n_in,
                              void* d_out, int out_size, void* d_ws, size_t ws_size,
                              hipStream_t stream){
  const int*   sentence = (const int*)  d_in[0];
  const int*   tags     = (const int*)  d_in[1];
  const float* emb      = (const float*)d_in[2];
  const float* w_ih_f   = (const float*)d_in[3];
  const float* w_hh_f   = (const float*)d_in[4];
  const float* b_ih_f   = (const float*)d_in[5];
  const float* b_hh_f   = (const float*)d_in[6];
  const float* w_ih_b   = (const float*)d_in[7];
  const float* w_hh_b   = (const float*)d_in[8];
  const float* b_ih_b   = (const float*)d_in[9];
  const float* b_hh_b   = (const float*)d_in[10];
  const float* h0       = (const float*)d_in[11];
  const float* c0       = (const float*)d_in[12];
  const float* w_out    = (const float*)d_in[13];
  const float* b_out    = (const float*)d_in[14];
  const float* trans    = (const float*)d_in[15];
  float* out = (float*)d_out;

  float* ws = (float*)d_ws;
  float* vxg    = ws;                                 // [2][8000][300] (permuted)
  float* featsF = vxg + (size_t)2 * VOCABN * G4;      // [512][256][6]
  float* featsB = featsF + (size_t)SS * BB * TT;      // [512][256][6]
  float* crfM   = featsB + (size_t)SS * BB * TT;      // [256][16][6][6]
  float* pgold  = crfM + (size_t)BB * NCH * 36;       // [256][16]

  k_gemm<<<2 * 63 * 5, 256, 0, stream>>>(emb, w_ih_f, w_ih_b,
                                         b_ih_f, b_hh_f, b_ih_b, b_hh_b, vxg);
  k_lstm<<<32, 640, 0, stream>>>(sentence, vxg, w_hh_f, w_hh_b, h0, c0, w_out, b_out,
                                 featsF, featsB);
  k_crf_scan<<<96 + 16, 256, 0, stream>>>(featsF, featsB, trans, tags, crfM, pgold);
  k_crf_comb<<<BB / 64, 64, 0, stream>>>(crfM, pgold, trans, tags, out);
}

// Round 11
// 529.274 us; speedup vs baseline: 3.0064x; 1.0413x over previous
//
#include <hip/hip_runtime.h>
#include <stdint.h>

#define VOCABN 8000
#define EE     300
#define HH     75
#define G4     300   // 4*H
#define TT     6
#define BB     256
#define SS     512
#define STARTT 4
#define STOPT  5
#define NEGV   (-10000.0f)
#define NCH    16    // CRF chunks
#define CHL    32    // steps per chunk

typedef __fp16 fp16x2 __attribute__((ext_vector_type(2)));
typedef __fp16 f16x8 __attribute__((ext_vector_type(8)));
typedef float f32x4 __attribute__((ext_vector_type(4)));
typedef unsigned int u32;

__device__ __forceinline__ float sigf(float x){
  return __builtin_amdgcn_rcpf(1.0f + __expf(-x));
}
__device__ __forceinline__ float tanhf_(float x){
  return __builtin_fmaf(__builtin_amdgcn_rcpf(1.0f + __expf(-2.0f * x)), 2.0f, -1.0f);
}
__device__ __forceinline__ float pk2(float a, float b){
  fp16x2 r = __builtin_amdgcn_cvt_pkrtz(a, b);
  return __builtin_bit_cast(float, r);
}
__device__ __forceinline__ float dot2pk(float a, float b, float c){
  asm("v_dot2_f32_f16 %0, %1, %2, %0" : "+v"(c) : "v"(a), "v"(b));
  return c;
}
// raw barrier: orders LDS, leaves global prefetches in flight
__device__ __forceinline__ void sync_lds(){
  __builtin_amdgcn_sched_barrier(0);
  asm volatile("s_waitcnt lgkmcnt(0)" ::: "memory");
  __builtin_amdgcn_s_barrier();
  __builtin_amdgcn_sched_barrier(0);
}

// ---------------- K1: vocab_xg[dir][v][g'] with PERMUTED gate order ----------
#define LDSR 20
__global__ __launch_bounds__(256) void k_gemm(
    const float* __restrict__ emb, const float* __restrict__ w_ih_f,
    const float* __restrict__ w_ih_b,
    const float* __restrict__ b_ih_f, const float* __restrict__ b_hh_f,
    const float* __restrict__ b_ih_b, const float* __restrict__ b_hh_b,
    float* __restrict__ vxg){
  __shared__ alignas(16) float a_sh[128 * LDSR];
  __shared__ alignas(16) float b_sh[64 * LDSR];
  __shared__ float bias_sh[64];
  const int bx = blockIdx.x;
  const int dir = bx / (63 * 5);
  const int rem = bx % (63 * 5);
  const int vt = rem / 5, gt = rem % 5;
  const int v0 = vt * 128, g0 = gt * 64;
  const int tid = threadIdx.x;
  const float* wdir = dir ? w_ih_b : w_ih_f;

  if (tid < 64){
    int g = g0 + tid;
    float bi = 0.f;
    if (g < G4) bi = dir ? (b_ih_b[g] + b_hh_b[g]) : (b_ih_f[g] + b_hh_f[g]);
    bias_sh[tid] = bi;
  }

  float acc[8][4];
  #pragma unroll
  for (int i = 0; i < 8; ++i)
    #pragma unroll
    for (int j = 0; j < 4; ++j) acc[i][j] = 0.f;

  const int tx = tid & 15, ty = tid >> 4;
  const int la_r = tid >> 1, la_h = (tid & 1) * 8;
  const int lb_r = tid >> 2, lb_h = (tid & 3) * 4;

  const int va = v0 + la_r;
  const float* arow = emb + (size_t)(va < VOCABN ? va : 0) * EE;
  const int gb = g0 + lb_r;
  const float* brow = wdir + (size_t)(gb < G4 ? gb : 0) * EE;
  const float4 z4 = {0.f, 0.f, 0.f, 0.f};

  for (int kk = 0; kk < 19; ++kk){
    const int e0 = kk * 16;
    float4 av0 = *(const float4*)&arow[e0 + la_h];
    float4 av1 = (e0 + la_h + 7 < EE) ? *(const float4*)&arow[e0 + la_h + 4] : z4;
    float4 bv  = (e0 + lb_h + 3 < EE) ? *(const float4*)&brow[e0 + lb_h]     : z4;
    __syncthreads();
    *(float4*)&a_sh[la_r * LDSR + la_h]     = av0;
    *(float4*)&a_sh[la_r * LDSR + la_h + 4] = av1;
    *(float4*)&b_sh[lb_r * LDSR + lb_h]     = bv;
    __syncthreads();
    #pragma unroll
    for (int e4 = 0; e4 < 4; ++e4){
      float4 bq[4], aq[8];
      #pragma unroll
      for (int j = 0; j < 4; ++j) bq[j] = *(const float4*)&b_sh[(tx + 16 * j) * LDSR + e4 * 4];
      #pragma unroll
      for (int i = 0; i < 8; ++i) aq[i] = *(const float4*)&a_sh[(ty + 16 * i) * LDSR + e4 * 4];
      #pragma unroll
      for (int i = 0; i < 8; ++i)
        #pragma unroll
        for (int j = 0; j < 4; ++j)
          acc[i][j] += aq[i].x * bq[j].x + aq[i].y * bq[j].y
                     + aq[i].z * bq[j].z + aq[i].w * bq[j].w;
    }
  }

  const size_t obase = (size_t)dir * VOCABN * G4;
  #pragma unroll
  for (int i = 0; i < 8; ++i){
    int v = v0 + ty + 16 * i;
    if (v < VOCABN){
      #pragma unroll
      for (int j = 0; j < 4; ++j){
        int g = g0 + tx + 16 * j;
        if (g < G4){
          int gp = 4 * (g % 75) + (g / 75);   // permuted gate index
          vxg[obase + (size_t)v * G4 + gp] = acc[i][j] + bias_sh[tx + 16 * j];
        }
      }
    }
  }
}

// ---------------- K2: MFMA BiLSTM, 16 batch per block ------------------------
// h stored in LDS in MFMA B-FRAGMENT ORDER hfrag[buf][k>>3][bb][k&7]:
// lane l's ds_read_b128 lands at byte l*16 -> zero bank conflicts (was 8-way
// at stride-208 = 2.6M conflict cycles). Writes: ds_write_b16 at banks
// (4bb+(q>>1))%32 -> 2-way = free.
__global__ __launch_bounds__(640) void k_lstm(
    const int* __restrict__ sentence, const float* __restrict__ vxg,
    const float* __restrict__ w_hh_f, const float* __restrict__ w_hh_b,
    const float* __restrict__ h0, const float* __restrict__ c0,
    const float* __restrict__ w_out, const float* __restrict__ b_out,
    float* __restrict__ featsF, float* __restrict__ featsB){
  __shared__ int tok_sh[SS * 16];
  __shared__ alignas(16) __fp16 hfrag[2][12 * 16 * 8];   // [buf][k>>3][bb][k&7]
  const int bx = blockIdx.x;
  const int dir = bx >> 4, group = bx & 15;
  const int t = threadIdx.x;
  const int w = t >> 6, lane = t & 63;
  const int bb = lane & 15, q = lane >> 4;
  const int T0 = 2 * w, T1 = 2 * w + 1;
  const int rbA = 16 * T0 + 4 * q, rbB = 16 * T1 + 4 * q;
  const int hA = rbA >> 2, hB = rbB >> 2;      // hA = 8w+q, hB = 8w+4+q
  const int bglob = group * 16 + bb;
  const int wiA = w * 128 + bb * 8 + q;        // fragment-order write indices
  const int wiB = w * 128 + bb * 8 + 4 + q;

  for (int i = t; i < 2 * 12 * 16 * 4; i += 640) ((u32*)hfrag)[i] = 0;
  for (int i = t; i < 16 * SS; i += 640){
    int bq = i >> 9, s = i & 511;
    tok_sh[s * 16 + ((bq + s) & 15)] = sentence[(size_t)(group * 16 + bq) * SS + s];
  }
  __syncthreads();

  const float* whh = dir ? w_hh_b : w_hh_f;
  f16x8 a00, a01, a02, a10, a11, a12;
  #define BUILD_A(dst, T, c) { \
    int m = 16 * (T) + bb; int kb = 32 * (c) + 8 * q; \
    _Pragma("unroll") \
    for (int j = 0; j < 8; ++j){ \
      int kk = kb + j; float wv = 0.f; \
      if (kk < HH){ \
        if (m < 300) wv = whh[((m & 3) * 75 + (m >> 2)) * HH + kk]; \
        else if (m < 306) wv = w_out[(m - 300) * (2 * HH) + dir * HH + kk]; \
      } \
      dst[j] = (__fp16)wv; } }
  BUILD_A(a00, T0, 0) BUILD_A(a01, T0, 1) BUILD_A(a02, T0, 2)
  BUILD_A(a10, T1, 0) BUILD_A(a11, T1, 1) BUILD_A(a12, T1, 2)

  float cA = 0.f, cB = 0.f;
  if (hA < HH){
    cA = c0[((size_t)dir * BB + bglob) * HH + hA];
    hfrag[0][wiA] = (__fp16)h0[((size_t)dir * BB + bglob) * HH + hA];
  }
  if (hB < HH){
    cB = c0[((size_t)dir * BB + bglob) * HH + hB];
    hfrag[0][wiB] = (__fp16)h0[((size_t)dir * BB + bglob) * HH + hB];
  }
  const float bo0 = dir ? 0.f : b_out[0], bo1 = dir ? 0.f : b_out[1];
  const float bo2 = dir ? 0.f : b_out[2], bo3 = dir ? 0.f : b_out[3];
  const float bo4 = dir ? 0.f : b_out[4], bo5 = dir ? 0.f : b_out[5];
  __syncthreads();

  const float* vx = vxg + (size_t)dir * VOCABN * G4;
  float* feats = dir ? featsB : featsF;
  const float4 zf4 = {0.f, 0.f, 0.f, 0.f};

  float4 cur0 = zf4, cur1 = zf4, nx0 = zf4, nx1 = zf4;
  {
    int p = dir ? (SS - 1) : 0;
    int tk = tok_sh[p * 16 + ((bb + p) & 15)];
    const float* base = vx + (size_t)tk * G4;
    if (hA < HH) cur0 = *(const float4*)(base + rbA);
    if (hB < HH) cur1 = *(const float4*)(base + rbB);
    p = dir ? (SS - 2) : 1;
    tk = tok_sh[p * 16 + ((bb + p) & 15)];
    base = vx + (size_t)tk * G4;
    if (hA < HH) nx0 = *(const float4*)(base + rbA);
    if (hB < HH) nx1 = *(const float4*)(base + rbB);
  }

  for (int k = 0; k <= SS; ++k){
    const __fp16* hq = hfrag[k & 1];
    f16x8 b0 = *(const f16x8*)&hq[(0 * 64 + lane) * 8];   // byte addr = lane*16
    f16x8 b1 = *(const f16x8*)&hq[(1 * 64 + lane) * 8];
    f16x8 b2 = *(const f16x8*)&hq[(2 * 64 + lane) * 8];

    float4 p0 = zf4, p1 = zf4;
    if (k + 2 < SS){                        // depth-2 xg prefetch
      int p = dir ? (SS - 3 - k) : (k + 2);
      int tk = tok_sh[p * 16 + ((bb + p) & 15)];
      const float* base = vx + (size_t)tk * G4;
      if (hA < HH) p0 = *(const float4*)(base + rbA);
      if (hB < HH) p1 = *(const float4*)(base + rbB);
    }

    f32x4 acc0 = {0.f, 0.f, 0.f, 0.f}, acc1 = {0.f, 0.f, 0.f, 0.f};
    asm("v_mfma_f32_16x16x32_f16 %0, %1, %2, %0" : "+v"(acc0) : "a"(a00), "v"(b0));
    asm("v_mfma_f32_16x16x32_f16 %0, %1, %2, %0" : "+v"(acc1) : "a"(a10), "v"(b0));
    asm("v_mfma_f32_16x16x32_f16 %0, %1, %2, %0" : "+v"(acc0) : "a"(a01), "v"(b1));
    asm("v_mfma_f32_16x16x32_f16 %0, %1, %2, %0" : "+v"(acc1) : "a"(a11), "v"(b1));
    asm("v_mfma_f32_16x16x32_f16 %0, %1, %2, %0" : "+v"(acc0) : "a"(a02), "v"(b2));
    asm("v_mfma_f32_16x16x32_f16 %0, %1, %2, %0" : "+v"(acc1) : "a"(a12), "v"(b2));

    __fp16* hw = hfrag[(k & 1) ^ 1];
    if (k < SS){
      if (hA < HH){
        float gi = acc0.x + cur0.x, gf = acc0.y + cur0.y;
        float gg = acc0.z + cur0.z, go = acc0.w + cur0.w;
        cA = sigf(gf) * cA + sigf(gi) * tanhf_(gg);
        hw[wiA] = (__fp16)(sigf(go) * tanhf_(cA));
      }
      if (hB < HH){
        float gi = acc1.x + cur1.x, gf = acc1.y + cur1.y;
        float gg = acc1.z + cur1.z, go = acc1.w + cur1.w;
        cB = sigf(gf) * cB + sigf(gi) * tanhf_(gg);
        hw[wiB] = (__fp16)(sigf(go) * tanhf_(cB));
      }
    }
    if (k >= 1){
      if (rbA == 300){                       // feat rows 0..3 (wave 9, q=3)
        int ps = dir ? (SS - k) : (k - 1);
        float* fb = feats + ((size_t)ps * BB + bglob) * TT;
        float2 v01 = {acc0.x + bo0, acc0.y + bo1};
        float2 v23 = {acc0.z + bo2, acc0.w + bo3};
        *(float2*)fb = v01;
        *(float2*)(fb + 2) = v23;
      }
      if (rbB == 304){                       // feat rows 4..5 (wave 9, q=0)
        int ps = dir ? (SS - k) : (k - 1);
        float* fb = feats + ((size_t)ps * BB + bglob) * TT;
        float2 v45 = {acc1.x + bo4, acc1.y + bo5};
        *(float2*)(fb + 4) = v45;
      }
    }
    cur0 = nx0; cur1 = nx1; nx0 = p0; nx1 = p1;
    sync_lds();
  }
}

// ---------------- K3a: CRF chunked alpha-scan + gold partials ----------------
#define LOADSTAGE(X0,X1,X2,Y0,Y1,Y2, srow) do{ \
  int _r = (srow); if (_r >= SS) _r = 0; \
  const float2* _pF = (const float2*)(featsF + ((size_t)_r * BB + b) * TT); \
  const float2* _pB = (const float2*)(featsB + ((size_t)_r * BB + b) * TT); \
  X0 = _pF[0]; X1 = _pF[1]; X2 = _pF[2]; \
  Y0 = _pB[0]; Y1 = _pB[1]; Y2 = _pB[2]; }while(0)

#define ASTEP(X0,X1,X2,Y0,Y1,Y2, srow) do{ \
  float F0 = X0.x + Y0.x, F1 = X0.y + Y0.y, F2 = X1.x + Y1.x; \
  float F3 = X1.y + Y1.y, F4 = X2.x + Y2.x, F5 = X2.y + Y2.y; \
  float M = fmaxf(fmaxf(fmaxf(a0,a1),fmaxf(a2,a3)),fmaxf(a4,a5)); \
  float p01 = pk2(__expf(a0-M), __expf(a1-M)); \
  float p23 = pk2(__expf(a2-M), __expf(a3-M)); \
  float p45 = pk2(__expf(a4-M), __expf(a5-M)); \
  float s0 = dot2pk(p45, Tq2,  dot2pk(p23, Tq1,  dot2pk(p01, Tq0,  0.f))); \
  float s1 = dot2pk(p45, Tq5,  dot2pk(p23, Tq4,  dot2pk(p01, Tq3,  0.f))); \
  float s2 = dot2pk(p45, Tq8,  dot2pk(p23, Tq7,  dot2pk(p01, Tq6,  0.f))); \
  float s3 = dot2pk(p45, Tq11, dot2pk(p23, Tq10, dot2pk(p01, Tq9,  0.f))); \
  float s4 = dot2pk(p45, Tq14, dot2pk(p23, Tq13, dot2pk(p01, Tq12, 0.f))); \
  float s5 = dot2pk(p45, Tq17, dot2pk(p23, Tq16, dot2pk(p01, Tq15, 0.f))); \
  a0 = M + __logf(fmaxf(s0, 1e-37f)) + F0;  a1 = M + __logf(fmaxf(s1, 1e-37f)) + F1; \
  a2 = M + __logf(fmaxf(s2, 1e-37f)) + F2;  a3 = M + __logf(fmaxf(s3, 1e-37f)) + F3; \
  a4 = M + __logf(fmaxf(s4, 1e-37f)) + F4;  a5 = M + __logf(fmaxf(s5, 1e-37f)) + F5; \
  LOADSTAGE(X0,X1,X2,Y0,Y1,Y2, (srow) + 2); }while(0)

__global__ __launch_bounds__(256) void k_crf_scan(
    const float* __restrict__ featsF, const float* __restrict__ featsB,
    const float* __restrict__ trans, const int* __restrict__ tags,
    float* __restrict__ crfM, float* __restrict__ pgold){
  __shared__ float tr_sh[36];
  __shared__ u32 etp_sh[18];
  const int tid = threadIdx.x;
  if (tid < 36) tr_sh[tid] = trans[tid];
  if (tid < 18) etp_sh[tid] = __float_as_uint(
      pk2(__expf(trans[2 * tid]), __expf(trans[2 * tid + 1])));
  __syncthreads();
  const int bx = blockIdx.x;

  if (bx < 96){
    const int g = bx * 256 + tid;
    const int s0i = g % 6;
    const int c = (g / 6) % NCH;
    const int b = g / (6 * NCH);
    const int cbase = c * CHL;

    float Tq0=__int_as_float(etp_sh[0]),  Tq1=__int_as_float(etp_sh[1]),
          Tq2=__int_as_float(etp_sh[2]),  Tq3=__int_as_float(etp_sh[3]),
          Tq4=__int_as_float(etp_sh[4]),  Tq5=__int_as_float(etp_sh[5]),
          Tq6=__int_as_float(etp_sh[6]),  Tq7=__int_as_float(etp_sh[7]),
          Tq8=__int_as_float(etp_sh[8]),  Tq9=__int_as_float(etp_sh[9]),
          Tq10=__int_as_float(etp_sh[10]), Tq11=__int_as_float(etp_sh[11]),
          Tq12=__int_as_float(etp_sh[12]), Tq13=__int_as_float(etp_sh[13]),
          Tq14=__int_as_float(etp_sh[14]), Tq15=__int_as_float(etp_sh[15]),
          Tq16=__int_as_float(etp_sh[16]), Tq17=__int_as_float(etp_sh[17]);

    float a0 = (s0i == 0) ? 0.f : NEGV, a1 = (s0i == 1) ? 0.f : NEGV;
    float a2 = (s0i == 2) ? 0.f : NEGV, a3 = (s0i == 3) ? 0.f : NEGV;
    float a4 = (s0i == 4) ? 0.f : NEGV, a5 = (s0i == 5) ? 0.f : NEGV;

    float2 xA0,xA1,xA2,yA0,yA1,yA2, xB0,xB1,xB2,yB0,yB1,yB2;
    LOADSTAGE(xA0,xA1,xA2,yA0,yA1,yA2, cbase + 0);
    LOADSTAGE(xB0,xB1,xB2,yB0,yB1,yB2, cbase + 1);
    for (int s = 0; s < CHL; s += 2){
      ASTEP(xA0,xA1,xA2,yA0,yA1,yA2, cbase + s);
      ASTEP(xB0,xB1,xB2,yB0,yB1,yB2, cbase + s + 1);
    }
    float* mrow = crfM + ((size_t)(b * NCH + c) * 6 + s0i) * 6;
    mrow[0] = a0; mrow[1] = a1; mrow[2] = a2;
    mrow[3] = a3; mrow[4] = a4; mrow[5] = a5;
  } else {
    const int g2 = (bx - 96) * 256 + tid;
    const int b = g2 / NCH;
    const int c = g2 % NCH;
    const int* tg = tags + (size_t)b * SS + c * CHL;
    int prev = (c == 0) ? STARTT : tg[-1];
    float acc = 0.f;
    #pragma unroll 4
    for (int s = 0; s < CHL; ++s){
      int ct = tg[s];
      size_t fo = (size_t)(c * CHL + s) * BB * TT + (size_t)b * TT + ct;
      acc += tr_sh[ct * 6 + prev] + featsF[fo] + featsB[fo];
      prev = ct;
    }
    pgold[b * NCH + c] = acc;
  }
}

// ---------------- K3b: combine 16 chunk matrices + finish -------------------
__global__ __launch_bounds__(64) void k_crf_comb(
    const float* __restrict__ crfM, const float* __restrict__ pgold,
    const float* __restrict__ trans, const int* __restrict__ tags,
    float* __restrict__ out){
  const int b = blockIdx.x * 64 + threadIdx.x;
  float v0 = NEGV, v1 = NEGV, v2 = NEGV, v3 = NEGV, v4 = 0.f, v5 = NEGV;
  for (int c = 0; c < NCH; ++c){
    const float* mb = crfM + (size_t)(b * NCH + c) * 36;
    float n[6];
    #pragma unroll
    for (int j = 0; j < 6; ++j){
      float t0 = v0 + mb[0 * 6 + j], t1 = v1 + mb[1 * 6 + j];
      float t2 = v2 + mb[2 * 6 + j], t3 = v3 + mb[3 * 6 + j];
      float t4 = v4 + mb[4 * 6 + j], t5 = v5 + mb[5 * 6 + j];
      float m = fmaxf(fmaxf(fmaxf(t0,t1),fmaxf(t2,t3)),fmaxf(t4,t5));
      float s = __expf(t0-m)+__expf(t1-m)+__expf(t2-m)
              + __expf(t3-m)+__expf(t4-m)+__expf(t5-m);
      n[j] = m + __logf(s);
    }
    v0 = n[0]; v1 = n[1]; v2 = n[2]; v3 = n[3]; v4 = n[4]; v5 = n[5];
  }
  float z0 = v0 + trans[30], z1 = v1 + trans[31], z2 = v2 + trans[32];
  float z3 = v3 + trans[33], z4 = v4 + trans[34], z5 = v5 + trans[35];
  float M2 = fmaxf(fmaxf(fmaxf(z0,z1),fmaxf(z2,z3)),fmaxf(z4,z5));
  float ss = __expf(z0-M2)+__expf(z1-M2)+__expf(z2-M2)
           + __expf(z3-M2)+__expf(z4-M2)+__expf(z5-M2);
  float fwd = M2 + __logf(ss);

  float gold = trans[STOPT * 6 + tags[(size_t)b * SS + SS - 1]];
  #pragma unroll
  for (int c = 0; c < NCH; ++c) gold += pgold[b * NCH + c];
  out[b] = fwd - gold;
}

// ---------------- launch -----------------------------------------------------
extern "C" void kernel_launch(void* const* d_in, const int* in_sizes, int n_in,
                              void* d_out, int out_size, void* d_ws, size_t ws_size,
                              hipStream_t stream){
  const int*   sentence = (const int*)  d_in[0];
  const int*   tags     = (const int*)  d_in[1];
  const float* emb      = (const float*)d_in[2];
  const float* w_ih_f   = (const float*)d_in[3];
  const float* w_hh_f   = (const float*)d_in[4];
  const float* b_ih_f   = (const float*)d_in[5];
  const float* b_hh_f   = (const float*)d_in[6];
  const float* w_ih_b   = (const float*)d_in[7];
  const float* w_hh_b   = (const float*)d_in[8];
  const float* b_ih_b   = (const float*)d_in[9];
  const float* b_hh_b   = (const float*)d_in[10];
  const float* h0       = (const float*)d_in[11];
  const float* c0       = (const float*)d_in[12];
  const float* w_out    = (const float*)d_in[13];
  const float* b_out    = (const float*)d_in[14];
  const float* trans    = (const float*)d_in[15];
  float* out = (float*)d_out;

  float* ws = (float*)d_ws;
  float* vxg    = ws;                                 // [2][8000][300] (permuted)
  float* featsF = vxg + (size_t)2 * VOCABN * G4;      // [512][256][6]
  float* featsB = featsF + (size_t)SS * BB * TT;      // [512][256][6]
  float* crfM   = featsB + (size_t)SS * BB * TT;      // [256][16][6][6]
  float* pgold  = crfM + (size_t)BB * NCH * 36;       // [256][16]

  k_gemm<<<2 * 63 * 5, 256, 0, stream>>>(emb, w_ih_f, w_ih_b,
                                         b_ih_f, b_hh_f, b_ih_b, b_hh_b, vxg);
  k_lstm<<<32, 640, 0, stream>>>(sentence, vxg, w_hh_f, w_hh_b, h0, c0, w_out, b_out,
                                 featsF, featsB);
  k_crf_scan<<<96 + 16, 256, 0, stream>>>(featsF, featsB, trans, tags, crfM, pgold);
  k_crf_comb<<<BB / 64, 64, 0, stream>>>(crfM, pgold, trans, tags, out);
}